// Round 2
// baseline (3492.863 us; speedup 1.0000x reference)
//
#include <hip/hip_runtime.h>
#include <hip/hip_bf16.h>

#define NPIX (96*128)   // 12288 pixels
#define DIMX 163

__device__ __forceinline__ float geluf(float x){ return 0.5f*x*(1.0f+erff(x*0.70710678118654752f)); }
__device__ __forceinline__ float eluf(float x){ return x>0.0f ? x : expm1f(x); }

struct Params {
  const float* rgb; const float* proj_err; const float* feat; const float* view_dir;
  const float* normal; const float* IL;
  const float *pw1,*pb1,*pw2,*pb2,*pw3,*pb3;
  const float *lnv_s,*lnv_b,*Wv,*Wout,*bout,*lnn_s,*lnn_b,*W1,*b1,*W2,*b2;
  const float *lnb_s,*lnb_b,*Wb1,*bb1,*Wb2,*bb2,*Wb3,*bb3;
  float* out;
};

// LayerNorm over 163 features for nrows rows. xT/xnT are [163][8] column-major
// (feature-major, row stride 8). 32 lanes per row compute stats, all threads
// then normalize.
__device__ __forceinline__ void ln_rows(const float* xT, float* xnT, int nrows,
                                        const float* sc, const float* bi,
                                        float* s_ln, int t)
{
  int r = t>>5, lane = t&31;
  if (r < nrows) {
    float sm=0.f, sq=0.f;
    for (int k=lane;k<DIMX;k+=32){ float v=xT[k*8+r]; sm+=v; sq+=v*v; }
    #pragma unroll
    for (int off=16;off;off>>=1){ sm+=__shfl_xor(sm,off,32); sq+=__shfl_xor(sq,off,32); }
    if (lane==0){
      float mean = sm*(1.f/163.f);
      float var  = sq*(1.f/163.f) - mean*mean;
      s_ln[r*2]   = mean;
      s_ln[r*2+1] = rsqrtf(var + 1e-5f);
    }
  }
  __syncthreads();
  for (int i=t;i<nrows*DIMX;i+=256){
    int rr = i/DIMX, c = i - rr*DIMX;
    float v = (xT[c*8+rr]-s_ln[rr*2])*s_ln[rr*2+1];
    xnT[c*8+rr] = v*sc[c] + bi[c];
  }
  __syncthreads();
}

__global__ __launch_bounds__(256)
void aggnet_kernel(Params P)
{
  const int t = threadIdx.x;
  const int p = blockIdx.x;   // pixel index, p = h*W + w

  // PBR weight LDS layout offsets (floats):
  // w1: 0..511  b1: 512..575  w2: 576..4671  b2: 4672..4735  w3: 4736..6783  b3: 6784..6815
  __shared__ float s_pbrw[6816];
  __shared__ float s_pin[96*8];
  __shared__ float s_mask[96];
  __shared__ float s_h[256];
  __shared__ float s_h2[256];
  __shared__ float s_pbr[96*32];
  __shared__ float s_xinT[DIMX*8];   // x_input, [feat][row]
  __shared__ float s_xT[DIMX*8];     // x
  __shared__ float s_xnT[DIMX*8];    // LN(x)
  __shared__ float s_x96T[96*8];     // [v | mean | var]
  __shared__ float s_yT[256*8];      // MLP hidden (and head scratch)
  __shared__ float s_wgt[8];
  __shared__ float s_ln[16];

  // ---- stage PBR weights into LDS ----
  for (int i=t;i<512;i+=256)  s_pbrw[i]      = P.pw1[i];
  for (int i=t;i<64;i+=256)   s_pbrw[512+i]  = P.pb1[i];
  for (int i=t;i<4096;i+=256) s_pbrw[576+i]  = P.pw2[i];
  for (int i=t;i<64;i+=256)   s_pbrw[4672+i] = P.pb2[i];
  for (int i=t;i<2048;i+=256) s_pbrw[4736+i] = P.pw3[i];
  for (int i=t;i<32;i+=256)   s_pbrw[6784+i] = P.pb3[i];

  // ---- geometry: one thread per (view n, light s) sample ----
  if (t < 96) {
    int n = t/12, s = t - n*12;
    const float* il = P.IL + (p*12 + s)*7;
    float ax=il[0], ay=il[1], az=il[2];
    float sharp = 1.f/(tanf(1.5692255304681f*il[3]) + 0.1f);
    float i0=tanf(1.5692255304681f*il[4]);
    float i1=tanf(1.5692255304681f*il[5]);
    float i2=tanf(1.5692255304681f*il[6]);
    const float* nr = P.normal + (p*12 + s)*3;
    float nx=nr[0], ny=nr[1], nz=nr[2];
    const float* vdp = P.view_dir + (p*8 + n)*3;
    float vx=vdp[0], vy=vdp[1], vz=vdp[2];
    float hx=ax+vx, hy=ay+vy, hz=az+vz;
    float hn = sqrtf(hx*hx+hy*hy+hz*hz);
    float inv = 1.f/fmaxf(hn, 1e-12f);
    hx*=inv; hy*=inv; hz*=inv;
    float NdotL = ax*nx+ay*ny+az*nz;
    float NdotV = vx*nx+vy*ny+vz*nz;
    float NdotH = nx*hx+ny*hy+nz*hz;
    float hdotV = hx*vx+hy*vy+hz*vz;
    float fres = 0.95f*exp2f((-5.55472f*hdotV - 6.98316f)*hdotV) + 0.05f;
    float* pin = &s_pin[t*8];
    pin[0]=NdotL; pin[1]=sharp; pin[2]=i0; pin[3]=i1; pin[4]=i2;
    pin[5]=NdotH*NdotH; pin[6]=NdotV; pin[7]=fres;
    s_mask[t] = (NdotL*(i0+i1+i2) > 0.f) ? 1.f : 0.f;
  }
  if (t>=96 && t<104) {
    int r=t-96;
    float pe = P.proj_err[p*8+r];
    s_wgt[r] = -fminf(log10f(fabsf(pe)+1e-6f), 0.f);
  }
  __syncthreads();
  if (t==0){
    float s=0.f;
    #pragma unroll
    for (int r=0;r<8;++r) s += s_wgt[r];
    float inv = 1.f/fmaxf(s,1e-12f);
    #pragma unroll
    for (int r=0;r<8;++r) s_wgt[r]*=inv;
  }
  __syncthreads();

  // ---- PBR MLP: 24 chunks of 4 samples x 64 hidden units ----
  {
    const int sl = t>>6, j = t&63;
    for (int ch=0; ch<24; ++ch) {
      const int g = ch*4 + sl;
      float acc = s_pbrw[512+j];
      #pragma unroll
      for (int k=0;k<8;++k) acc += s_pin[g*8+k]*s_pbrw[k*64+j];
      s_h[sl*64+j] = eluf(acc);
      __syncthreads();
      acc = s_pbrw[4672+j];
      #pragma unroll
      for (int k=0;k<64;++k) acc += s_h[sl*64+k]*s_pbrw[576+k*64+j];
      s_h2[sl*64+j] = eluf(acc);
      __syncthreads();
      if (t<128) {
        int sm=t>>5, cc=t&31;
        int g2 = ch*4+sm;
        float a = s_pbrw[6784+cc];
        #pragma unroll
        for (int k=0;k<64;++k) a += s_h2[sm*64+k]*s_pbrw[4736+k*32+cc];
        s_pbr[g2*32+cc] = s_mask[g2]*a;
      }
      __syncthreads();
    }
  }

  // ---- light = sum_s pbr*mask ; assemble x_input (163 = 3 rgb + 32 light + 128 feat) ----
  {
    int n=t>>5, c=t&31;
    float lt=0.f;
    #pragma unroll
    for (int s=0;s<12;++s) lt += s_pbr[(n*12+s)*32+c];
    s_xinT[(3+c)*8+n] = lt;
    if (t<24){ int r=t/3, cc=t-r*3; s_xinT[cc*8+r] = P.rgb[(p*8+r)*3+cc]; }
    for (int i=t;i<1024;i+=256){ int cc=i>>3, r=i&7; s_xinT[(35+cc)*8+r] = P.feat[cc*NPIX+p]; }
  }
  __syncthreads();
  for (int i=t;i<DIMX*8;i+=256) s_xT[i]=s_xinT[i];
  __syncthreads();

  // ---- main loop, DEPTH=2 ----
  for (int L=0; L<2; ++L) {
    ln_rows(s_xT, s_xnT, 8, P.lnv_s+L*DIMX, P.lnv_b+L*DIMX, s_ln, t);
    // v = LN(x) @ Wv[L]  -> x96 cols 0..31
    {
      int r=t>>5, c=t&31;
      const float* wv = P.Wv + L*DIMX*32;
      float acc=0.f;
      for (int k=0;k<DIMX;++k) acc += s_xnT[k*8+r]*wv[k*32+c];
      s_x96T[c*8+r]=acc;
    }
    __syncthreads();
    // weighted mean/var over views -> x96 cols 32..63 / 64..95 (broadcast to rows)
    if (t<32){
      float m=0.f;
      #pragma unroll
      for (int r=0;r<8;++r) m += s_x96T[t*8+r]*s_wgt[r];
      float va=0.f;
      #pragma unroll
      for (int r=0;r<8;++r){ float d=s_x96T[t*8+r]-m; va+=s_wgt[r]*d*d; }
      #pragma unroll
      for (int r=0;r<8;++r){ s_x96T[(32+t)*8+r]=m; s_x96T[(64+t)*8+r]=va; }
    }
    __syncthreads();
    if (L==0){
      // x = x96 @ Wout[0] + bout[0] + x_input   (8 rows)
      for (int i=t;i<DIMX*8;i+=256){
        int r=i/DIMX, c=i-r*DIMX;
        float acc = P.bout[c] + s_xinT[c*8+r];
        for (int k=0;k<96;++k) acc += s_x96T[k*8+r]*P.Wout[k*DIMX+c];
        s_xT[c*8+r]=acc;
      }
      __syncthreads();
      ln_rows(s_xT, s_xnT, 8, P.lnn_s, P.lnn_b, s_ln, t);
      // y = gelu(LN(x) @ W1[0] + b1[0])  -- thread owns a column, 8 rows
      {
        int c=t;
        float b1v = P.b1[c];
        float acc[8];
        #pragma unroll
        for (int r=0;r<8;++r) acc[r]=b1v;
        for (int k=0;k<DIMX;++k){
          float w = P.W1[k*256+c];
          const float4* xp = (const float4*)&s_xnT[k*8];
          float4 a=xp[0], b=xp[1];
          acc[0]+=a.x*w; acc[1]+=a.y*w; acc[2]+=a.z*w; acc[3]+=a.w*w;
          acc[4]+=b.x*w; acc[5]+=b.y*w; acc[6]+=b.z*w; acc[7]+=b.w*w;
        }
        float* yp=&s_yT[c*8];
        #pragma unroll
        for (int r=0;r<8;++r) yp[r]=geluf(acc[r]);
      }
      __syncthreads();
      // x = y @ W2[0] + b2[0] + x_input
      for (int i=t;i<DIMX*8;i+=256){
        int r=i/DIMX, c=i-r*DIMX;
        float acc = P.b2[c] + s_xinT[c*8+r];
        for (int k=0;k<256;++k) acc += s_yT[k*8+r]*P.W2[k*DIMX+c];
        s_xT[c*8+r]=acc;
      }
      __syncthreads();
    } else {
      // last layer: only row 0
      if (t<DIMX){
        int c=t;
        float acc=P.bout[DIMX+c] + s_xinT[c*8];
        for (int k=0;k<96;++k) acc += s_x96T[k*8]*P.Wout[96*DIMX + k*DIMX+c];
        s_xT[c*8]=acc;
      }
      __syncthreads();
      ln_rows(s_xT, s_xnT, 1, P.lnn_s+DIMX, P.lnn_b+DIMX, s_ln, t);
      {
        int c=t;
        float acc=P.b1[256+c];
        for (int k=0;k<DIMX;++k) acc += s_xnT[k*8]*P.W1[DIMX*256 + k*256+c];
        s_yT[c*8]=geluf(acc);
      }
      __syncthreads();
      if (t<DIMX){
        int c=t;
        float acc=P.b2[DIMX+c] + s_xinT[c*8];
        for (int k=0;k<256;++k) acc += s_yT[k*8]*P.W2[256*DIMX + k*DIMX+c];
        s_xT[c*8]=acc;
      }
      __syncthreads();
    }
  }

  // ---- output head (row 0 only) ----
  ln_rows(s_xT, s_xnT, 1, P.lnb_s, P.lnb_b, s_ln, t);
  if (t<128){
    float acc=P.bb1[t];
    for (int k=0;k<DIMX;++k) acc += s_xnT[k*8]*P.Wb1[k*128+t];
    s_yT[1536+t]=geluf(acc);
  }
  __syncthreads();
  if (t<128){
    float acc=P.bb2[t];
    for (int k=0;k<128;++k) acc += s_yT[1536+k]*P.Wb2[k*128+t];
    s_yT[1792+t]=geluf(acc);
  }
  __syncthreads();
  if (t<64){
    float acc=P.bb3[t];
    for (int k=0;k<128;++k) acc += s_yT[1792+k]*P.Wb3[k*64+t];
    // output layout (1, 64, H, W): channel-major
    P.out[t*NPIX+p] = acc;
  }
}

extern "C" void kernel_launch(void* const* d_in, const int* in_sizes, int n_in,
                              void* d_out, int out_size, void* d_ws, size_t ws_size,
                              hipStream_t stream)
{
  Params P;
  P.rgb      = (const float*)d_in[0];
  // d_in[1..3]: shading / spec_feat / spec_in — unused scalars
  P.proj_err = (const float*)d_in[4];
  P.feat     = (const float*)d_in[5];
  P.view_dir = (const float*)d_in[6];
  P.normal   = (const float*)d_in[7];
  P.IL       = (const float*)d_in[8];
  P.pw1=(const float*)d_in[9];  P.pb1=(const float*)d_in[10];
  P.pw2=(const float*)d_in[11]; P.pb2=(const float*)d_in[12];
  P.pw3=(const float*)d_in[13]; P.pb3=(const float*)d_in[14];
  P.lnv_s=(const float*)d_in[15]; P.lnv_b=(const float*)d_in[16];
  P.Wv=(const float*)d_in[17]; P.Wout=(const float*)d_in[18]; P.bout=(const float*)d_in[19];
  P.lnn_s=(const float*)d_in[20]; P.lnn_b=(const float*)d_in[21];
  P.W1=(const float*)d_in[22]; P.b1=(const float*)d_in[23];
  P.W2=(const float*)d_in[24]; P.b2=(const float*)d_in[25];
  P.lnb_s=(const float*)d_in[26]; P.lnb_b=(const float*)d_in[27];
  P.Wb1=(const float*)d_in[28]; P.bb1=(const float*)d_in[29];
  P.Wb2=(const float*)d_in[30]; P.bb2=(const float*)d_in[31];
  P.Wb3=(const float*)d_in[32]; P.bb3=(const float*)d_in[33];
  P.out = (float*)d_out;

  hipLaunchKernelGGL(aggnet_kernel, dim3(NPIX), dim3(256), 0, stream, P);
}

// Round 3
// 843.701 us; speedup vs baseline: 4.1399x; 4.1399x over previous
//
#include <hip/hip_runtime.h>
#include <hip/hip_bf16.h>

#define NPIX 12288
#define DIM 163
#define PXB 4          // pixels per block
#define RB  32         // rows per block (PXB*8 views)
#define NTHR 512

// LDS strides (bf16 elements) - chosen for 16B alignment + low bank conflict
#define SXIN 200
#define SX   200
#define SY   264
#define SH   72
#define SPIN 40
#define SX96 104
#define SX8  200

// ws layout offsets (bf16 elements)
#define OFF_PW1  0
#define OFF_PW2  2048
#define OFF_PW3  6144
#define OFF_WV0  8192
#define OFF_WV1  14336
#define OFF_WO0  20480
#define OFF_WO1  37376
#define OFF_W10  54272
#define OFF_W11  103424
#define OFF_W20  152576
#define OFF_W21  197632
#define OFF_WB1  242688
#define OFF_WB2  267264
#define OFF_WB3  283648
#define WS_ELEMS 291840
#define WS_BYTES (WS_ELEMS*2)

typedef short bf16x8 __attribute__((ext_vector_type(8)));
typedef float f32x4 __attribute__((ext_vector_type(4)));
#define MFMA(a,b,c) __builtin_amdgcn_mfma_f32_16x16x32_bf16(a,b,c,0,0,0)

struct Params {
  const float* rgb; const float* proj_err; const float* feat; const float* view_dir;
  const float* normal; const float* IL;
  const float *pw1,*pb1,*pw2,*pb2,*pw3,*pb3;
  const float *lnv_s,*lnv_b,*Wv,*Wout,*bout,*lnn_s,*lnn_b,*W1,*b1,*W2,*b2;
  const float *lnb_s,*lnb_b,*Wb1,*bb1,*Wb2,*bb2,*Wb3,*bb3;
  float* out;
};

__device__ __forceinline__ float b2f(unsigned short u){
  union{unsigned int i; float f;} v; v.i = ((unsigned int)u)<<16; return v.f;
}
__device__ __forceinline__ unsigned short f2b(float f){
  __hip_bfloat16 h = __float2bfloat16(f);
  return *reinterpret_cast<unsigned short*>(&h);
}
__device__ __forceinline__ float geluf(float x){ return 0.5f*x*(1.0f+erff(x*0.70710678118654752f)); }
__device__ __forceinline__ float eluf(float x){ return x>0.0f ? x : expm1f(x); }

// Plain A-fragment: lane holds A[m0+(l&15)][kt*32+(l>>4)*8 + j], j=0..7
__device__ __forceinline__ bf16x8 afrag(const unsigned short* base, int stride, int m0, int kt, int lane){
  const unsigned short* p = base + (m0 + (lane&15))*stride + kt*32 + ((lane>>4)<<3);
  return *(const bf16x8*)p;
}
// A-fragment with on-the-fly LayerNorm affine. S/B are padded to 192 with zeros,
// so padded/junk cols produce exactly 0 (guards NaN only via finite inputs).
__device__ __forceinline__ bf16x8 afrag_ln(const unsigned short* base, int stride, int m0, int kt, int lane,
                                           const float* stats, const float* S, const float* Bb){
  int row = m0 + (lane&15);
  int c0  = kt*32 + ((lane>>4)<<3);
  bf16x8 raw = *(const bf16x8*)(base + row*stride + c0);
  float mu = stats[row*2], inv = stats[row*2+1];
  bf16x8 out;
  #pragma unroll
  for (int j=0;j<8;++j){
    float v = (b2f((unsigned short)raw[j]) - mu)*inv;
    v = v*S[c0+j] + Bb[c0+j];
    out[j] = (short)f2b(v);
  }
  return out;
}
// B-fragment from pre-swizzled ws
__device__ __forceinline__ bf16x8 bfrag(const unsigned short* ws, int NT, int kt, int nt, int lane){
  return *(const bf16x8*)(ws + ((((kt*NT + nt)<<6) + lane)<<3));
}

// LN stats: 16 lanes per row over 163 cols (bf16 in LDS), fp32 accumulate.
__device__ __forceinline__ void ln_stats(const unsigned short* xb, int stride, int nrows, float* stats, int t){
  int row = t>>4, sl = t&15;
  if (row < nrows){
    float sm=0.f, sq=0.f;
    for (int c=sl; c<DIM; c+=16){ float v=b2f(xb[row*stride+c]); sm+=v; sq+=v*v; }
    #pragma unroll
    for (int o=8;o;o>>=1){ sm+=__shfl_xor(sm,o,16); sq+=__shfl_xor(sq,o,16); }
    if (sl==0){
      float mu = sm*(1.f/163.f);
      float va = sq*(1.f/163.f) - mu*mu;
      stats[row*2] = mu; stats[row*2+1] = rsqrtf(va + 1e-5f);
    }
  }
}

// ---------------- weight conversion kernel (fp32 -> bf16 B-frag swizzled) ----------------
__global__ __launch_bounds__(512)
void conv_weights(Params P, unsigned short* ws){
  int idx = blockIdx.x*512 + threadIdx.x;
  if (idx >= WS_ELEMS) return;
  const float* src; int K,N,NT; int off;
  if      (idx < OFF_PW2){ src=P.pw1;           K=8;  N=64;  NT=4;  off=OFF_PW1; }
  else if (idx < OFF_PW3){ src=P.pw2;           K=64; N=64;  NT=4;  off=OFF_PW2; }
  else if (idx < OFF_WV0){ src=P.pw3;           K=64; N=32;  NT=2;  off=OFF_PW3; }
  else if (idx < OFF_WV1){ src=P.Wv;            K=163;N=32;  NT=2;  off=OFF_WV0; }
  else if (idx < OFF_WO0){ src=P.Wv+163*32;     K=163;N=32;  NT=2;  off=OFF_WV1; }
  else if (idx < OFF_WO1){ src=P.Wout;          K=96; N=163; NT=11; off=OFF_WO0; }
  else if (idx < OFF_W10){ src=P.Wout+96*163;   K=96; N=163; NT=11; off=OFF_WO1; }
  else if (idx < OFF_W11){ src=P.W1;            K=163;N=256; NT=16; off=OFF_W10; }
  else if (idx < OFF_W20){ src=P.W1+163*256;    K=163;N=256; NT=16; off=OFF_W11; }
  else if (idx < OFF_W21){ src=P.W2;            K=256;N=163; NT=11; off=OFF_W20; }
  else if (idx < OFF_WB1){ src=P.W2+256*163;    K=256;N=163; NT=11; off=OFF_W21; }
  else if (idx < OFF_WB2){ src=P.Wb1;           K=163;N=128; NT=8;  off=OFF_WB1; }
  else if (idx < OFF_WB3){ src=P.Wb2;           K=128;N=128; NT=8;  off=OFF_WB2; }
  else                   { src=P.Wb3;           K=128;N=64;  NT=4;  off=OFF_WB3; }
  int rel = idx - off;
  int j = rel & 7, l = (rel>>3)&63, fi = rel>>9;
  int nt = fi % NT, kt = fi / NT;
  int k = kt*32 + ((l>>4)<<3) + j;
  int n = nt*16 + (l&15);
  float v = (k < K && n < N) ? src[(size_t)k*N + n] : 0.f;
  ws[idx] = f2b(v);
}

// ---------------- main kernel ----------------
__global__ __launch_bounds__(512)
void aggnet_mfma(Params P, const unsigned short* ws)
{
  const int t = threadIdx.x;
  const int lane = t & 63;
  const int w = t >> 6;              // wave 0..7
  const int p0 = blockIdx.x * PXB;   // pixel base

  __shared__ __align__(16) unsigned short ls_xin[RB*SXIN];  // 12800 B
  __shared__ __align__(16) unsigned short ls_x[RB*SX];      // 12800 B
  __shared__ __align__(16) char ls_union[22784];
  __shared__ float ls_light[RB*33];
  __shared__ float ls_lnS[192], ls_lnB[192];
  __shared__ float ls_bias[256], ls_bias2[256];
  __shared__ float ls_stats[RB*2];
  __shared__ float ls_wgt[RB];
  __shared__ float ls_mask[96];
  __shared__ float ls_pb1[64], ls_pb2[64], ls_pb3[32];

  // union views
  unsigned short* pin   = (unsigned short*)ls_union;              // [96][40]  PBR
  unsigned short* hbuf  = (unsigned short*)(ls_union + 7680);     // [96][72]  PBR
  float*          vbuf  = (float*)ls_union;                       // [32][36]  main
  unsigned short* x96   = (unsigned short*)(ls_union + 4608);     // [32][104] L0
  unsigned short* ybuf  = (unsigned short*)ls_union;              // [32][264] L0 mlp
  unsigned short* x96r0 = (unsigned short*)(ls_union + 4608);     // [16][104] L1
  unsigned short* x8    = (unsigned short*)(ls_union + 7936);     // [16][200] L1/head
  unsigned short* y8    = (unsigned short*)(ls_union + 14336);    // [16][264] L1/head

  const unsigned short* wsPW1 = ws + OFF_PW1;
  const unsigned short* wsPW2 = ws + OFF_PW2;
  const unsigned short* wsPW3 = ws + OFF_PW3;
  const unsigned short* wsWv[2]  = { ws+OFF_WV0, ws+OFF_WV1 };
  const unsigned short* wsWo[2]  = { ws+OFF_WO0, ws+OFF_WO1 };
  const unsigned short* wsW1[2]  = { ws+OFF_W10, ws+OFF_W11 };
  const unsigned short* wsW2[2]  = { ws+OFF_W20, ws+OFF_W21 };

  // ---------------- phase 0: init ----------------
  for (int i=t;i<RB*33;i+=NTHR) ls_light[i]=0.f;
  for (int i=t;i<96*24;i+=NTHR){ int rr=i/24, c=8+i%24; pin[rr*SPIN+c]=0; }   // pin K-pad
  for (int i=t;i<RB*37;i+=NTHR){ int rr=i/37, c=163+i%37; ls_xin[rr*SXIN+c]=0; ls_x[rr*SX+c]=0; }
  for (int i=t;i<64;i+=NTHR){ ls_pb1[i]=P.pb1[i]; ls_pb2[i]=P.pb2[i]; }
  for (int i=t;i<32;i+=NTHR) ls_pb3[i]=P.pb3[i];
  if (t < RB){
    int px=t>>3, vv=t&7;
    float pe = P.proj_err[(size_t)(p0+px)*8+vv];
    ls_wgt[t] = -fminf(log10f(fabsf(pe)+1e-6f), 0.f);
  }
  __syncthreads();
  if (t < PXB){
    float s=0.f;
    #pragma unroll
    for (int vv=0;vv<8;++vv) s += ls_wgt[t*8+vv];
    float inv = 1.f/fmaxf(s,1e-12f);
    #pragma unroll
    for (int vv=0;vv<8;++vv) ls_wgt[t*8+vv]*=inv;
  }
  __syncthreads();

  // ---------------- phase 1: PBR MLP, 4 chunks of 8 rows (96 samples) ----------------
  for (int ch=0; ch<4; ++ch){
    // geometry
    if (t < 96){
      int rl = t/12, s = t%12;
      int r = ch*8 + rl;
      int Pp = p0 + (r>>3), n = r&7;
      const float* il = P.IL + ((size_t)Pp*12 + s)*7;
      float ax=il[0], ay=il[1], az=il[2];
      float sharp = 1.f/(tanf(1.5692255304681f*il[3]) + 0.1f);
      float i0=tanf(1.5692255304681f*il[4]);
      float i1=tanf(1.5692255304681f*il[5]);
      float i2=tanf(1.5692255304681f*il[6]);
      const float* nr = P.normal + ((size_t)Pp*12 + s)*3;
      float nx=nr[0], ny=nr[1], nz=nr[2];
      const float* vdp = P.view_dir + ((size_t)Pp*8 + n)*3;
      float vx=vdp[0], vy=vdp[1], vz=vdp[2];
      float hx=ax+vx, hy=ay+vy, hz=az+vz;
      float hn = sqrtf(hx*hx+hy*hy+hz*hz);
      float inv = 1.f/fmaxf(hn, 1e-12f);
      hx*=inv; hy*=inv; hz*=inv;
      float NdotL = ax*nx+ay*ny+az*nz;
      float NdotV = vx*nx+vy*ny+vz*nz;
      float NdotH = nx*hx+ny*hy+nz*hz;
      float hdotV = hx*vx+hy*vy+hz*vz;
      float fres = 0.95f*exp2f((-5.55472f*hdotV - 6.98316f)*hdotV) + 0.05f;
      unsigned short* pp = &pin[t*SPIN];
      pp[0]=f2b(NdotL); pp[1]=f2b(sharp); pp[2]=f2b(i0); pp[3]=f2b(i1); pp[4]=f2b(i2);
      pp[5]=f2b(NdotH*NdotH); pp[6]=f2b(NdotV); pp[7]=f2b(fres);
      ls_mask[t] = (NdotL*(i0+i1+i2) > 0.f) ? 1.f : 0.f;
    }
    __syncthreads();
    // L1: 6mt x 4nt, K=32 (padded from 8)  -> h
    #pragma unroll
    for (int q=0;q<3;++q){
      int u = w + q*8;
      int mt = u>>2, nt = u&3;
      bf16x8 a = afrag(pin, SPIN, mt*16, 0, lane);
      f32x4 d = {0.f,0.f,0.f,0.f};
      d = MFMA(a, bfrag(wsPW1, 4, 0, nt, lane), d);
      int col = nt*16 + (lane&15);
      #pragma unroll
      for (int jj=0;jj<4;++jj){
        int sm = mt*16 + ((lane>>4)<<2) + jj;
        hbuf[sm*SH+col] = f2b(eluf(d[jj] + ls_pb1[col]));
      }
    }
    __syncthreads();
    // L2: 6mt x 4nt, K=64 -> hold -> h (in place)
    {
      f32x4 dq[3];
      #pragma unroll
      for (int q=0;q<3;++q){
        int u = w + q*8;
        int mt = u>>2, nt = u&3;
        f32x4 d = {0.f,0.f,0.f,0.f};
        #pragma unroll
        for (int kt=0;kt<2;++kt)
          d = MFMA(afrag(hbuf, SH, mt*16, kt, lane), bfrag(wsPW2, 4, kt, nt, lane), d);
        dq[q] = d;
      }
      __syncthreads();
      #pragma unroll
      for (int q=0;q<3;++q){
        int u = w + q*8;
        int mt = u>>2, nt = u&3;
        int col = nt*16 + (lane&15);
        #pragma unroll
        for (int jj=0;jj<4;++jj){
          int sm = mt*16 + ((lane>>4)<<2) + jj;
          hbuf[sm*SH+col] = f2b(eluf(dq[q][jj] + ls_pb2[col]));
        }
      }
    }
    __syncthreads();
    // L3: 6mt x 2nt, K=64 -> mask -> atomic light
    #pragma unroll
    for (int q=0;q<2;++q){
      int u = w + q*8;
      if (u < 12){
        int mt = u>>1, nt = u&1;
        f32x4 d = {0.f,0.f,0.f,0.f};
        #pragma unroll
        for (int kt=0;kt<2;++kt)
          d = MFMA(afrag(hbuf, SH, mt*16, kt, lane), bfrag(wsPW3, 2, kt, nt, lane), d);
        int col = nt*16 + (lane&15);
        #pragma unroll
        for (int jj=0;jj<4;++jj){
          int sm = mt*16 + ((lane>>4)<<2) + jj;
          float val = (d[jj] + ls_pb3[col]) * ls_mask[sm];
          int rr = ch*8 + sm/12;
          atomicAdd(&ls_light[rr*33+col], val);
        }
      }
    }
    __syncthreads();
  }

  // ---------------- phase 2: assemble x_input ----------------
  for (int i=t;i<RB*3;i+=NTHR){
    int r=i/3, c=i%3;
    ls_xin[r*SXIN+c] = f2b(P.rgb[((size_t)(p0+(r>>3))*8 + (r&7))*3 + c]);
  }
  for (int i=t;i<RB*32;i+=NTHR){
    int r=i>>5, c=i&31;
    ls_xin[r*SXIN+3+c] = f2b(ls_light[r*33+c]);
  }
  for (int i=t;i<RB*128;i+=NTHR){
    int r=i>>7, c=i&127;
    ls_xin[r*SXIN+35+c] = f2b(P.feat[(size_t)c*NPIX + p0 + (r>>3)]);
  }
  __syncthreads();

  // ---------------- main layers ----------------
  for (int L=0; L<2; ++L){
    const unsigned short* xsrc = (L==0)? ls_xin : ls_x;
    // LN stats (lnv) + stage scale/bias
    ln_stats(xsrc, SXIN, RB, ls_stats, t);
    for (int i=t;i<192;i+=NTHR){
      ls_lnS[i] = (i<163)? P.lnv_s[L*163+i] : 0.f;
      ls_lnB[i] = (i<163)? P.lnv_b[L*163+i] : 0.f;
    }
    __syncthreads();
    // Wv: 2mt x 2nt, K=192  (A affine) -> vbuf f32
    if (w < 4){
      int mt = w&1, nt = w>>1;
      bf16x8 a[6];
      #pragma unroll
      for (int kt=0;kt<6;++kt) a[kt] = afrag_ln(xsrc, SXIN, mt*16, kt, lane, ls_stats, ls_lnS, ls_lnB);
      f32x4 d = {0.f,0.f,0.f,0.f};
      #pragma unroll
      for (int kt=0;kt<6;++kt) d = MFMA(a[kt], bfrag(wsWv[L], 2, kt, nt, lane), d);
      int col = nt*16 + (lane&15);
      #pragma unroll
      for (int jj=0;jj<4;++jj){
        int row = mt*16 + ((lane>>4)<<2) + jj;
        vbuf[row*36+col] = d[jj];
      }
    }
    __syncthreads();

    if (L==0){
      // build x96 = [v | m | var], stage bout
      for (int i=t;i<RB*32;i+=NTHR){ int rr=i>>5, c=i&31; x96[rr*SX96+c] = f2b(vbuf[rr*36+c]); }
      if (t < 128){
        int px=t>>5, c=t&31;
        float m=0.f;
        #pragma unroll
        for (int vv=0;vv<8;++vv) m += ls_wgt[px*8+vv]*vbuf[(px*8+vv)*36+c];
        float va=0.f;
        #pragma unroll
        for (int vv=0;vv<8;++vv){ float dd=vbuf[(px*8+vv)*36+c]-m; va += ls_wgt[px*8+vv]*dd*dd; }
        unsigned short mb=f2b(m), vb=f2b(va);
        #pragma unroll
        for (int vv=0;vv<8;++vv){ int rr=px*8+vv; x96[rr*SX96+32+c]=mb; x96[rr*SX96+64+c]=vb; }
      }
      for (int i=t;i<163;i+=NTHR) ls_bias[i] = P.bout[i];
      __syncthreads();
      // Wout: 2mt x 11nt, K=96 -> s_x (+bout +xin)
      {
        int mt = w&1;
        bf16x8 a[3];
        #pragma unroll
        for (int kt=0;kt<3;++kt) a[kt] = afrag(x96, SX96, mt*16, kt, lane);
        for (int nt=(w>>1); nt<11; nt+=4){
          f32x4 d = {0.f,0.f,0.f,0.f};
          #pragma unroll
          for (int kt=0;kt<3;++kt) d = MFMA(a[kt], bfrag(wsWo[0], 11, kt, nt, lane), d);
          int col = nt*16 + (lane&15);
          if (col < 163){
            #pragma unroll
            for (int jj=0;jj<4;++jj){
              int row = mt*16 + ((lane>>4)<<2) + jj;
              ls_x[row*SX+col] = f2b(d[jj] + ls_bias[col] + b2f(ls_xin[row*SXIN+col]));
            }
          }
        }
      }
      __syncthreads();
      // LN stats (lnn0) + stage, b1->bias, b2->bias2
      ln_stats(ls_x, SX, RB, ls_stats, t);
      for (int i=t;i<192;i+=NTHR){
        ls_lnS[i] = (i<163)? P.lnn_s[i] : 0.f;
        ls_lnB[i] = (i<163)? P.lnn_b[i] : 0.f;
      }
      for (int i=t;i<256;i+=NTHR) ls_bias[i] = P.b1[i];
      for (int i=t;i<163;i+=NTHR) ls_bias2[i] = P.b2[i];
      __syncthreads();
      // W1: 2mt x 16nt, K=192 (A affine) -> y = gelu
      {
        int mt = w&1;
        bf16x8 a[6];
        #pragma unroll
        for (int kt=0;kt<6;++kt) a[kt] = afrag_ln(ls_x, SX, mt*16, kt, lane, ls_stats, ls_lnS, ls_lnB);
        for (int nt=(w>>1); nt<16; nt+=4){
          f32x4 d = {0.f,0.f,0.f,0.f};
          #pragma unroll
          for (int kt=0;kt<6;++kt) d = MFMA(a[kt], bfrag(wsW1[0], 16, kt, nt, lane), d);
          int col = nt*16 + (lane&15);
          #pragma unroll
          for (int jj=0;jj<4;++jj){
            int row = mt*16 + ((lane>>4)<<2) + jj;
            ybuf[row*SY+col] = f2b(geluf(d[jj] + ls_bias[col]));
          }
        }
      }
      __syncthreads();
      // W2: 2mt x 11nt, K=256 -> s_x (+b2 +xin)
      {
        int mt = w&1;
        bf16x8 a[8];
        #pragma unroll
        for (int kt=0;kt<8;++kt) a[kt] = afrag(ybuf, SY, mt*16, kt, lane);
        for (int nt=(w>>1); nt<11; nt+=4){
          f32x4 d = {0.f,0.f,0.f,0.f};
          #pragma unroll
          for (int kt=0;kt<8;++kt) d = MFMA(a[kt], bfrag(wsW2[0], 11, kt, nt, lane), d);
          int col = nt*16 + (lane&15);
          if (col < 163){
            #pragma unroll
            for (int jj=0;jj<4;++jj){
              int row = mt*16 + ((lane>>4)<<2) + jj;
              ls_x[row*SX+col] = f2b(d[jj] + ls_bias2[col] + b2f(ls_xin[row*SXIN+col]));
            }
          }
        }
      }
      __syncthreads();
    } else {
      // layer 1 tail: row0 only per pixel
      // mean/var -> x96r0 rows=px ; zero x8 pad cols; stage bout1
      if (t < 128){
        int px=t>>5, c=t&31;
        float m=0.f;
        #pragma unroll
        for (int vv=0;vv<8;++vv) m += ls_wgt[px*8+vv]*vbuf[(px*8+vv)*36+c];
        float va=0.f;
        #pragma unroll
        for (int vv=0;vv<8;++vv){ float dd=vbuf[(px*8+vv)*36+c]-m; va += ls_wgt[px*8+vv]*dd*dd; }
        x96r0[px*SX96+c]    = f2b(vbuf[(px*8)*36+c]);
        x96r0[px*SX96+32+c] = f2b(m);
        x96r0[px*SX96+64+c] = f2b(va);
      }
      for (int i=t;i<16*37;i+=NTHR){ int rr=i/37, c=163+i%37; x8[rr*SX8+c]=0; }
      for (int i=t;i<163;i+=NTHR) ls_bias[i] = P.bout[163+i];
      __syncthreads();
      // Wout1: 1mt x 11nt, K=96 -> x8 (+bout1 +xin row0)
      {
        bf16x8 a[3];
        #pragma unroll
        for (int kt=0;kt<3;++kt) a[kt] = afrag(x96r0, SX96, 0, kt, lane);
        for (int nt=w; nt<11; nt+=8){
          f32x4 d = {0.f,0.f,0.f,0.f};
          #pragma unroll
          for (int kt=0;kt<3;++kt) d = MFMA(a[kt], bfrag(wsWo[1], 11, kt, nt, lane), d);
          int col = nt*16 + (lane&15);
          if (col < 163){
            #pragma unroll
            for (int jj=0;jj<4;++jj){
              int px = ((lane>>4)<<2) + jj;
              if (px < PXB)
                x8[px*SX8+col] = f2b(d[jj] + ls_bias[col] + b2f(ls_xin[(px*8)*SXIN+col]));
            }
          }
        }
      }
      __syncthreads();
      // LN stats x8 (lnn1) + stage, b1_1->bias, b2_1->bias2
      ln_stats(x8, SX8, 16, ls_stats, t);
      for (int i=t;i<192;i+=NTHR){
        ls_lnS[i] = (i<163)? P.lnn_s[163+i] : 0.f;
        ls_lnB[i] = (i<163)? P.lnn_b[163+i] : 0.f;
      }
      for (int i=t;i<256;i+=NTHR) ls_bias[i] = P.b1[256+i];
      for (int i=t;i<163;i+=NTHR) ls_bias2[i] = P.b2[163+i];
      __syncthreads();
      // W1_1: 1mt x 16nt K=192 affine -> y8 gelu
      {
        bf16x8 a[6];
        #pragma unroll
        for (int kt=0;kt<6;++kt) a[kt] = afrag_ln(x8, SX8, 0, kt, lane, ls_stats, ls_lnS, ls_lnB);
        for (int nt=w; nt<16; nt+=8){
          f32x4 d = {0.f,0.f,0.f,0.f};
          #pragma unroll
          for (int kt=0;kt<6;++kt) d = MFMA(a[kt], bfrag(wsW1[1], 16, kt, nt, lane), d);
          int col = nt*16 + (lane&15);
          #pragma unroll
          for (int jj=0;jj<4;++jj){
            int row = ((lane>>4)<<2) + jj;
            y8[row*SY+col] = f2b(geluf(d[jj] + ls_bias[col]));
          }
        }
      }
      __syncthreads();
      // W2_1: 1mt x 11nt K=256 -> x8 (+b2_1 +xin row0)
      {
        bf16x8 a[8];
        #pragma unroll
        for (int kt=0;kt<8;++kt) a[kt] = afrag(y8, SY, 0, kt, lane);
        for (int nt=w; nt<11; nt+=8){
          f32x4 d = {0.f,0.f,0.f,0.f};
          #pragma unroll
          for (int kt=0;kt<8;++kt) d = MFMA(a[kt], bfrag(wsW2[1], 11, kt, nt, lane), d);
          int col = nt*16 + (lane&15);
          if (col < 163){
            #pragma unroll
            for (int jj=0;jj<4;++jj){
              int px = ((lane>>4)<<2) + jj;
              if (px < PXB)
                x8[px*SX8+col] = f2b(d[jj] + ls_bias2[col] + b2f(ls_xin[(px*8)*SXIN+col]));
            }
          }
        }
      }
      __syncthreads();
    }
  }

  // ---------------- head ----------------
  // LN stats x8 (lnb) + stage bb1->bias, bb2->bias2
  ln_stats(x8, SX8, 16, ls_stats, t);
  for (int i=t;i<192;i+=NTHR){
    ls_lnS[i] = (i<163)? P.lnb_s[i] : 0.f;
    ls_lnB[i] = (i<163)? P.lnb_b[i] : 0.f;
  }
  for (int i=t;i<128;i+=NTHR){ ls_bias[i] = P.bb1[i]; ls_bias2[i] = P.bb2[i]; }
  __syncthreads();
  // Wb1: K=192 affine, 8nt -> y8 gelu
  {
    bf16x8 a[6];
    #pragma unroll
    for (int kt=0;kt<6;++kt) a[kt] = afrag_ln(x8, SX8, 0, kt, lane, ls_stats, ls_lnS, ls_lnB);
    int nt = w;
    f32x4 d = {0.f,0.f,0.f,0.f};
    #pragma unroll
    for (int kt=0;kt<6;++kt) d = MFMA(a[kt], bfrag(ws+OFF_WB1, 8, kt, nt, lane), d);
    int col = nt*16 + (lane&15);
    #pragma unroll
    for (int jj=0;jj<4;++jj){
      int row = ((lane>>4)<<2) + jj;
      y8[row*SY+col] = f2b(geluf(d[jj] + ls_bias[col]));
    }
  }
  __syncthreads();
  // Wb2: K=128, 8nt -> hold -> y8 gelu ; stage bb3
  {
    bf16x8 a[4];
    #pragma unroll
    for (int kt=0;kt<4;++kt) a[kt] = afrag(y8, SY, 0, kt, lane);
    int nt = w;
    f32x4 d = {0.f,0.f,0.f,0.f};
    #pragma unroll
    for (int kt=0;kt<4;++kt) d = MFMA(a[kt], bfrag(ws+OFF_WB2, 8, kt, nt, lane), d);
    __syncthreads();
    int col = nt*16 + (lane&15);
    #pragma unroll
    for (int jj=0;jj<4;++jj){
      int row = ((lane>>4)<<2) + jj;
      y8[row*SY+col] = f2b(geluf(d[jj] + ls_bias2[col]));
    }
    for (int i=t;i<64;i+=NTHR) ls_bias[i] = P.bb3[i];
  }
  __syncthreads();
  // Wb3: K=128, 4nt -> global out
  if (w < 4){
    bf16x8 a[4];
    #pragma unroll
    for (int kt=0;kt<4;++kt) a[kt] = afrag(y8, SY, 0, kt, lane);
    int nt = w;
    f32x4 d = {0.f,0.f,0.f,0.f};
    #pragma unroll
    for (int kt=0;kt<4;++kt) d = MFMA(a[kt], bfrag(ws+OFF_WB3, 4, kt, nt, lane), d);
    int col = nt*16 + (lane&15);
    #pragma unroll
    for (int jj=0;jj<4;++jj){
      int px = ((lane>>4)<<2) + jj;
      if (px < PXB)
        P.out[(size_t)col*NPIX + p0 + px] = d[jj] + ls_bias[col];
    }
  }
}

// ================= fallback (round-2 fp32 kernel) for tiny ws =================
__device__ __forceinline__ void ln_rows_fb(const float* xT, float* xnT, int nrows,
                                           const float* sc, const float* bi,
                                           float* s_ln, int t)
{
  int r = t>>5, ln = t&31;
  if (r < nrows){
    float sm=0.f, sq=0.f;
    for (int k=ln;k<DIM;k+=32){ float v=xT[k*8+r]; sm+=v; sq+=v*v; }
    #pragma unroll
    for (int off=16;off;off>>=1){ sm+=__shfl_xor(sm,off,32); sq+=__shfl_xor(sq,off,32); }
    if (ln==0){
      float mean = sm*(1.f/163.f);
      float var  = sq*(1.f/163.f) - mean*mean;
      s_ln[r*2]=mean; s_ln[r*2+1]=rsqrtf(var+1e-5f);
    }
  }
  __syncthreads();
  for (int i=t;i<nrows*DIM;i+=256){
    int rr=i/DIM, c=i-rr*DIM;
    float v=(xT[c*8+rr]-s_ln[rr*2])*s_ln[rr*2+1];
    xnT[c*8+rr]=v*sc[c]+bi[c];
  }
  __syncthreads();
}

__global__ __launch_bounds__(256)
void aggnet_fallback(Params P)
{
  const int t = threadIdx.x;
  const int p = blockIdx.x;
  __shared__ float s_pbrw[6816];
  __shared__ float s_pin[96*8];
  __shared__ float s_mask[96];
  __shared__ float s_h[256];
  __shared__ float s_h2[256];
  __shared__ float s_pbr[96*32];
  __shared__ float s_xinT[DIM*8];
  __shared__ float s_xT[DIM*8];
  __shared__ float s_xnT[DIM*8];
  __shared__ float s_x96T[96*8];
  __shared__ float s_yT[256*8];
  __shared__ float s_wgt[8];
  __shared__ float s_ln[16];

  for (int i=t;i<512;i+=256)  s_pbrw[i]      = P.pw1[i];
  for (int i=t;i<64;i+=256)   s_pbrw[512+i]  = P.pb1[i];
  for (int i=t;i<4096;i+=256) s_pbrw[576+i]  = P.pw2[i];
  for (int i=t;i<64;i+=256)   s_pbrw[4672+i] = P.pb2[i];
  for (int i=t;i<2048;i+=256) s_pbrw[4736+i] = P.pw3[i];
  for (int i=t;i<32;i+=256)   s_pbrw[6784+i] = P.pb3[i];
  if (t < 96){
    int n = t/12, s = t - n*12;
    const float* il = P.IL + (p*12 + s)*7;
    float ax=il[0], ay=il[1], az=il[2];
    float sharp = 1.f/(tanf(1.5692255304681f*il[3]) + 0.1f);
    float i0=tanf(1.5692255304681f*il[4]);
    float i1=tanf(1.5692255304681f*il[5]);
    float i2=tanf(1.5692255304681f*il[6]);
    const float* nr = P.normal + (p*12 + s)*3;
    float nx=nr[0], ny=nr[1], nz=nr[2];
    const float* vdp = P.view_dir + (p*8 + n)*3;
    float vx=vdp[0], vy=vdp[1], vz=vdp[2];
    float hx=ax+vx, hy=ay+vy, hz=az+vz;
    float hn = sqrtf(hx*hx+hy*hy+hz*hz);
    float inv = 1.f/fmaxf(hn, 1e-12f);
    hx*=inv; hy*=inv; hz*=inv;
    float NdotL = ax*nx+ay*ny+az*nz;
    float NdotV = vx*nx+vy*ny+vz*nz;
    float NdotH = nx*hx+ny*hy+nz*hz;
    float hdotV = hx*vx+hy*vy+hz*vz;
    float fres = 0.95f*exp2f((-5.55472f*hdotV - 6.98316f)*hdotV) + 0.05f;
    float* pi2 = &s_pin[t*8];
    pi2[0]=NdotL; pi2[1]=sharp; pi2[2]=i0; pi2[3]=i1; pi2[4]=i2;
    pi2[5]=NdotH*NdotH; pi2[6]=NdotV; pi2[7]=fres;
    s_mask[t] = (NdotL*(i0+i1+i2) > 0.f) ? 1.f : 0.f;
  }
  if (t>=96 && t<104){
    int r=t-96;
    float pe = P.proj_err[p*8+r];
    s_wgt[r] = -fminf(log10f(fabsf(pe)+1e-6f), 0.f);
  }
  __syncthreads();
  if (t==0){
    float s=0.f;
    #pragma unroll
    for (int r=0;r<8;++r) s += s_wgt[r];
    float inv = 1.f/fmaxf(s,1e-12f);
    #pragma unroll
    for (int r=0;r<8;++r) s_wgt[r]*=inv;
  }
  __syncthreads();
  {
    const int sl = t>>6, j = t&63;
    for (int ch=0; ch<24; ++ch){
      const int g = ch*4 + sl;
      float acc = s_pbrw[512+j];
      #pragma unroll
      for (int k=0;k<8;++k) acc += s_pin[g*8+k]*s_pbrw[k*64+j];
      s_h[sl*64+j] = eluf(acc);
      __syncthreads();
      acc = s_pbrw[4672+j];
      #pragma unroll
      for (int k=0;k<64;++k) acc += s_h[sl*64+k]*s_pbrw[576+k*64+j];
      s_h2[sl*64+j] = eluf(acc);
      __syncthreads();
      if (t<128){
        int sm=t>>5, cc=t&31;
        int g2 = ch*4+sm;
        float a = s_pbrw[6784+cc];
        #pragma unroll
        for (int k=0;k<64;++k) a += s_h2[sm*64+k]*s_pbrw[4736+k*32+cc];
        s_pbr[g2*32+cc] = s_mask[g2]*a;
      }
      __syncthreads();
    }
  }
  {
    int n=t>>5, c=t&31;
    float lt=0.f;
    #pragma unroll
    for (int s=0;s<12;++s) lt += s_pbr[(n*12+s)*32+c];
    s_xinT[(3+c)*8+n] = lt;
    if (t<24){ int r=t/3, cc=t-r*3; s_xinT[cc*8+r] = P.rgb[(p*8+r)*3+cc]; }
    for (int i=t;i<1024;i+=256){ int cc=i>>3, r=i&7; s_xinT[(35+cc)*8+r] = P.feat[cc*NPIX+p]; }
  }
  __syncthreads();
  for (int i=t;i<DIM*8;i+=256) s_xT[i]=s_xinT[i];
  __syncthreads();
  for (int L=0; L<2; ++L){
    ln_rows_fb(s_xT, s_xnT, 8, P.lnv_s+L*DIM, P.lnv_b+L*DIM, s_ln, t);
    {
      int r=t>>5, c=t&31;
      const float* wv = P.Wv + L*DIM*32;
      float acc=0.f;
      for (int k=0;k<DIM;++k) acc += s_xnT[k*8+r]*wv[k*32+c];
      s_x96T[c*8+r]=acc;
    }
    __syncthreads();
    if (t<32){
      float m=0.f;
      #pragma unroll
      for (int r=0;r<8;++r) m += s_x96T[t*8+r]*s_wgt[r];
      float va=0.f;
      #pragma unroll
      for (int r=0;r<8;++r){ float d=s_x96T[t*8+r]-m; va+=s_wgt[r]*d*d; }
      #pragma unroll
      for (int r=0;r<8;++r){ s_x96T[(32+t)*8+r]=m; s_x96T[(64+t)*8+r]=va; }
    }
    __syncthreads();
    if (L==0){
      for (int i=t;i<DIM*8;i+=256){
        int r=i/DIM, c=i-r*DIM;
        float acc = P.bout[c] + s_xinT[c*8+r];
        for (int k=0;k<96;++k) acc += s_x96T[k*8+r]*P.Wout[k*DIM+c];
        s_xT[c*8+r]=acc;
      }
      __syncthreads();
      ln_rows_fb(s_xT, s_xnT, 8, P.lnn_s, P.lnn_b, s_ln, t);
      {
        int c=t;
        float b1v = P.b1[c];
        float acc[8];
        #pragma unroll
        for (int r=0;r<8;++r) acc[r]=b1v;
        for (int k=0;k<DIM;++k){
          float wv = P.W1[k*256+c];
          const float4* xp = (const float4*)&s_xnT[k*8];
          float4 a=xp[0], b=xp[1];
          acc[0]+=a.x*wv; acc[1]+=a.y*wv; acc[2]+=a.z*wv; acc[3]+=a.w*wv;
          acc[4]+=b.x*wv; acc[5]+=b.y*wv; acc[6]+=b.z*wv; acc[7]+=b.w*wv;
        }
        float* yp=&s_yT[c*8];
        #pragma unroll
        for (int r=0;r<8;++r) yp[r]=geluf(acc[r]);
      }
      __syncthreads();
      for (int i=t;i<DIM*8;i+=256){
        int r=i/DIM, c=i-r*DIM;
        float acc = P.b2[c] + s_xinT[c*8+r];
        for (int k=0;k<256;++k) acc += s_yT[k*8+r]*P.W2[k*DIM+c];
        s_xT[c*8+r]=acc;
      }
      __syncthreads();
    } else {
      if (t<DIM){
        int c=t;
        float acc=P.bout[DIM+c] + s_xinT[c*8];
        for (int k=0;k<96;++k) acc += s_x96T[k*8]*P.Wout[96*DIM + k*DIM+c];
        s_xT[c*8]=acc;
      }
      __syncthreads();
      ln_rows_fb(s_xT, s_xnT, 1, P.lnn_s+DIM, P.lnn_b+DIM, s_ln, t);
      {
        int c=t;
        float acc=P.b1[256+c];
        for (int k=0;k<DIM;++k) acc += s_xnT[k*8]*P.W1[DIM*256 + k*256+c];
        s_yT[c*8]=geluf(acc);
      }
      __syncthreads();
      if (t<DIM){
        int c=t;
        float acc=P.b2[DIM+c] + s_xinT[c*8];
        for (int k=0;k<256;++k) acc += s_yT[k*8]*P.W2[256*DIM + k*DIM+c];
        s_xT[c*8]=acc;
      }
      __syncthreads();
    }
  }
  ln_rows_fb(s_xT, s_xnT, 1, P.lnb_s, P.lnb_b, s_ln, t);
  if (t<128){
    float acc=P.bb1[t];
    for (int k=0;k<DIM;++k) acc += s_xnT[k*8]*P.Wb1[k*128+t];
    s_yT[1536+t]=geluf(acc);
  }
  __syncthreads();
  if (t<128){
    float acc=P.bb2[t];
    for (int k=0;k<128;++k) acc += s_yT[1536+k]*P.Wb2[k*128+t];
    s_yT[1792+t]=geluf(acc);
  }
  __syncthreads();
  if (t<64){
    float acc=P.bb3[t];
    for (int k=0;k<128;++k) acc += s_yT[1792+k]*P.Wb3[k*64+t];
    P.out[t*NPIX+p] = acc;
  }
}

extern "C" void kernel_launch(void* const* d_in, const int* in_sizes, int n_in,
                              void* d_out, int out_size, void* d_ws, size_t ws_size,
                              hipStream_t stream)
{
  Params P;
  P.rgb      = (const float*)d_in[0];
  P.proj_err = (const float*)d_in[4];
  P.feat     = (const float*)d_in[5];
  P.view_dir = (const float*)d_in[6];
  P.normal   = (const float*)d_in[7];
  P.IL       = (const float*)d_in[8];
  P.pw1=(const float*)d_in[9];  P.pb1=(const float*)d_in[10];
  P.pw2=(const float*)d_in[11]; P.pb2=(const float*)d_in[12];
  P.pw3=(const float*)d_in[13]; P.pb3=(const float*)d_in[14];
  P.lnv_s=(const float*)d_in[15]; P.lnv_b=(const float*)d_in[16];
  P.Wv=(const float*)d_in[17]; P.Wout=(const float*)d_in[18]; P.bout=(const float*)d_in[19];
  P.lnn_s=(const float*)d_in[20]; P.lnn_b=(const float*)d_in[21];
  P.W1=(const float*)d_in[22]; P.b1=(const float*)d_in[23];
  P.W2=(const float*)d_in[24]; P.b2=(const float*)d_in[25];
  P.lnb_s=(const float*)d_in[26]; P.lnb_b=(const float*)d_in[27];
  P.Wb1=(const float*)d_in[28]; P.bb1=(const float*)d_in[29];
  P.Wb2=(const float*)d_in[30]; P.bb2=(const float*)d_in[31];
  P.Wb3=(const float*)d_in[32]; P.bb3=(const float*)d_in[33];
  P.out = (float*)d_out;

  if (ws_size >= (size_t)WS_BYTES){
    unsigned short* ws = (unsigned short*)d_ws;
    hipLaunchKernelGGL(conv_weights, dim3((WS_ELEMS+511)/512), dim3(512), 0, stream, P, ws);
    hipLaunchKernelGGL(aggnet_mfma, dim3(NPIX/PXB), dim3(512), 0, stream, P, (const unsigned short*)ws);
  } else {
    hipLaunchKernelGGL(aggnet_fallback, dim3(NPIX), dim3(256), 0, stream, P);
  }
}

// Round 4
// 661.533 us; speedup vs baseline: 5.2800x; 1.2754x over previous
//
#include <hip/hip_runtime.h>
#include <hip/hip_bf16.h>

#define NPIX 12288
#define DIM 163
#define PXB 4          // pixels per block
#define RB  32         // rows per block (PXB*8 views)
#define NTHR 512

// LDS strides (bf16 elements). NOTE: strides for K=192-read buffers must be
// >=192 and give a non-multiple-of-32 dword row stride (bank spread): 200.
#define SXIN 200
#define SX   200
#define SY   264
#define SH   72
#define SPIN 40
#define SX96 104
#define SX8  200

// ws layout offsets (bf16 elements)
#define OFF_PW1  0
#define OFF_PW2  2048
#define OFF_PW3  6144
#define OFF_WV0  8192
#define OFF_WV1  14336
#define OFF_WO0  20480
#define OFF_WO1  37376
#define OFF_W10  54272
#define OFF_W11  103424
#define OFF_W20  152576
#define OFF_W21  197632
#define OFF_WB1  242688
#define OFF_WB2  267264
#define OFF_WB3  283648
#define WS_ELEMS 291840
#define WS_BYTES (WS_ELEMS*2)

typedef short bf16x8 __attribute__((ext_vector_type(8)));
typedef float f32x4 __attribute__((ext_vector_type(4)));
#define MFMA(a,b,c) __builtin_amdgcn_mfma_f32_16x16x32_bf16(a,b,c,0,0,0)

struct Params {
  const float* rgb; const float* proj_err; const float* feat; const float* view_dir;
  const float* normal; const float* IL;
  const float *pw1,*pb1,*pw2,*pb2,*pw3,*pb3;
  const float *lnv_s,*lnv_b,*Wv,*Wout,*bout,*lnn_s,*lnn_b,*W1,*b1,*W2,*b2;
  const float *lnb_s,*lnb_b,*Wb1,*bb1,*Wb2,*bb2,*Wb3,*bb3;
  float* out;
};

__device__ __forceinline__ float b2f(unsigned short u){
  union{unsigned int i; float f;} v; v.i = ((unsigned int)u)<<16; return v.f;
}
__device__ __forceinline__ unsigned short f2b(float f){
  __hip_bfloat16 h = __float2bfloat16(f);
  return *reinterpret_cast<unsigned short*>(&h);
}
// tan via HW sin/cos (args in (0, pi/2*0.999), no reduction needed)
__device__ __forceinline__ float tanhw(float u){
  float a = 1.5692255304681f*u;
  return __fdividef(__sinf(a), __cosf(a));
}
// elu: exp(x)-1 for x<0 (abs err ~1e-7, fine under bf16 quantization)
__device__ __forceinline__ float eluf(float x){ return x>0.0f ? x : __expf(x)-1.0f; }
// exact-ish gelu via A&S 7.1.26 erf (|eps|<=1.5e-7) + hw exp
__device__ __forceinline__ float geluf(float x){
  float z = fabsf(x)*0.70710678118654752f;
  float t = __fdividef(1.0f, 1.0f + 0.3275911f*z);
  float poly = t*(0.254829592f + t*(-0.284496736f + t*(1.421413741f + t*(-1.453152027f + t*1.061405429f))));
  float er = 1.0f - poly*__expf(-z*z);
  float s = (x >= 0.0f) ? er : -er;
  return 0.5f*x*(1.0f+s);
}

// Plain A-fragment: lane holds A[m0+(l&15)][kt*32+(l>>4)*8 + j], j=0..7
__device__ __forceinline__ bf16x8 afrag(const unsigned short* base, int stride, int m0, int kt, int lane){
  const unsigned short* p = base + (m0 + (lane&15))*stride + kt*32 + ((lane>>4)<<3);
  return *(const bf16x8*)p;
}
// A-fragment with on-the-fly LayerNorm affine. S/B padded to 192 with zeros.
// Pad x cols must hold FINITE values (NaN would poison even with S=0).
__device__ __forceinline__ bf16x8 afrag_ln(const unsigned short* base, int stride, int m0, int kt, int lane,
                                           const float* stats, const float* S, const float* Bb){
  int row = m0 + (lane&15);
  int c0  = kt*32 + ((lane>>4)<<3);
  bf16x8 raw = *(const bf16x8*)(base + row*stride + c0);
  float mu = stats[row*2], inv = stats[row*2+1];
  bf16x8 out;
  #pragma unroll
  for (int j=0;j<8;++j){
    float v = (b2f((unsigned short)raw[j]) - mu)*inv;
    v = v*S[c0+j] + Bb[c0+j];
    out[j] = (short)f2b(v);
  }
  return out;
}
// B-fragment from pre-swizzled ws
__device__ __forceinline__ bf16x8 bfrag(const unsigned short* ws, int NT, int kt, int nt, int lane){
  return *(const bf16x8*)(ws + ((((kt*NT + nt)<<6) + lane)<<3));
}

// LN stats: 16 lanes per row over 163 cols (bf16 in LDS), fp32 accumulate.
__device__ __forceinline__ void ln_stats(const unsigned short* xb, int stride, int nrows, float* stats, int t){
  int row = t>>4, sl = t&15;
  if (row < nrows){
    float sm=0.f, sq=0.f;
    for (int c=sl; c<DIM; c+=16){ float v=b2f(xb[row*stride+c]); sm+=v; sq+=v*v; }
    #pragma unroll
    for (int o=8;o;o>>=1){ sm+=__shfl_xor(sm,o,16); sq+=__shfl_xor(sq,o,16); }
    if (sl==0){
      float mu = sm*(1.f/163.f);
      float va = sq*(1.f/163.f) - mu*mu;
      stats[row*2] = mu; stats[row*2+1] = rsqrtf(va + 1e-5f);
    }
  }
}

// ---------------- weight conversion kernel (fp32 -> bf16 B-frag swizzled) ----------------
__global__ __launch_bounds__(512)
void conv_weights(Params P, unsigned short* ws){
  int idx = blockIdx.x*512 + threadIdx.x;
  if (idx >= WS_ELEMS) return;
  const float* src; int K,N,NT; int off;
  if      (idx < OFF_PW2){ src=P.pw1;           K=8;  N=64;  NT=4;  off=OFF_PW1; }
  else if (idx < OFF_PW3){ src=P.pw2;           K=64; N=64;  NT=4;  off=OFF_PW2; }
  else if (idx < OFF_WV0){ src=P.pw3;           K=64; N=32;  NT=2;  off=OFF_PW3; }
  else if (idx < OFF_WV1){ src=P.Wv;            K=163;N=32;  NT=2;  off=OFF_WV0; }
  else if (idx < OFF_WO0){ src=P.Wv+163*32;     K=163;N=32;  NT=2;  off=OFF_WV1; }
  else if (idx < OFF_WO1){ src=P.Wout;          K=96; N=163; NT=11; off=OFF_WO0; }
  else if (idx < OFF_W10){ src=P.Wout+96*163;   K=96; N=163; NT=11; off=OFF_WO1; }
  else if (idx < OFF_W11){ src=P.W1;            K=163;N=256; NT=16; off=OFF_W10; }
  else if (idx < OFF_W20){ src=P.W1+163*256;    K=163;N=256; NT=16; off=OFF_W11; }
  else if (idx < OFF_W21){ src=P.W2;            K=256;N=163; NT=11; off=OFF_W20; }
  else if (idx < OFF_WB1){ src=P.W2+256*163;    K=256;N=163; NT=11; off=OFF_W21; }
  else if (idx < OFF_WB2){ src=P.Wb1;           K=163;N=128; NT=8;  off=OFF_WB1; }
  else if (idx < OFF_WB3){ src=P.Wb2;           K=128;N=128; NT=8;  off=OFF_WB2; }
  else                   { src=P.Wb3;           K=128;N=64;  NT=4;  off=OFF_WB3; }
  int rel = idx - off;
  int j = rel & 7, l = (rel>>3)&63, fi = rel>>9;
  int nt = fi % NT, kt = fi / NT;
  int k = kt*32 + ((l>>4)<<3) + j;
  int n = nt*16 + (l&15);
  float v = (k < K && n < N) ? src[(size_t)k*N + n] : 0.f;
  ws[idx] = f2b(v);
}

// ---------------- main kernel ----------------
__global__ __launch_bounds__(512, 6)
void aggnet_mfma(Params P, const unsigned short* ws)
{
  const int t = threadIdx.x;
  const int lane = t & 63;
  const int w = t >> 6;              // wave 0..7
  const int p0 = blockIdx.x * PXB;   // pixel base

  __shared__ __align__(16) unsigned short ls_xin[RB*SXIN];  // 12800 B
  __shared__ __align__(16) unsigned short ls_x[RB*SX];      // 12800 B (light overlays start)
  __shared__ __align__(16) char ls_union[22784];
  __shared__ float ls_lnS[192], ls_lnB[192];
  __shared__ float ls_bias[256], ls_bias2[256];
  __shared__ float ls_stats[RB*2];
  __shared__ float ls_wgt[RB];
  __shared__ float ls_mask[96];
  __shared__ float ls_pb1[64], ls_pb2[64], ls_pb3[32];

  // union views
  unsigned short* pin   = (unsigned short*)ls_union;              // [96][40]  PBR in
  unsigned short* hbuf  = (unsigned short*)(ls_union + 7680);     // [96][72]  PBR hidden
  float*          pbrF  = (float*)ls_union;                       // [96][33]  PBR out (clobbers pin/hbuf head)
  float*          vbuf  = (float*)ls_union;                       // [32][36]  main v
  unsigned short* x96   = (unsigned short*)(ls_union + 4608);     // [32][104] L0
  unsigned short* ybuf  = (unsigned short*)ls_union;              // [32][264] L0 mlp hidden
  unsigned short* x96r0 = (unsigned short*)(ls_union + 4608);     // [16][104] L1
  unsigned short* x8    = (unsigned short*)(ls_union + 7936);     // [16][200] L1/head
  unsigned short* y8    = (unsigned short*)(ls_union + 14336);    // [16][264] L1/head
  float*          lightF = (float*)ls_x;                          // [32][33]  light accumulator

  const unsigned short* wsPW1 = ws + OFF_PW1;
  const unsigned short* wsPW2 = ws + OFF_PW2;
  const unsigned short* wsPW3 = ws + OFF_PW3;
  const unsigned short* wsWv[2]  = { ws+OFF_WV0, ws+OFF_WV1 };
  const unsigned short* wsWo[2]  = { ws+OFF_WO0, ws+OFF_WO1 };
  const unsigned short* wsW1[2]  = { ws+OFF_W10, ws+OFF_W11 };
  const unsigned short* wsW2[2]  = { ws+OFF_W20, ws+OFF_W21 };

  // ---------------- phase 0: init ----------------
  for (int i=t;i<RB*37;i+=NTHR){ int rr=i/37, c=163+i%37; ls_xin[rr*SXIN+c]=0; }
  for (int i=t;i<64;i+=NTHR){ ls_pb1[i]=P.pb1[i]; ls_pb2[i]=P.pb2[i]; }
  for (int i=t;i<32;i+=NTHR) ls_pb3[i]=P.pb3[i];
  if (t < RB){
    int px=t>>3, vv=t&7;
    float pe = P.proj_err[(size_t)(p0+px)*8+vv];
    ls_wgt[t] = -fminf(log10f(fabsf(pe)+1e-6f), 0.f);
  }
  __syncthreads();
  if (t < PXB){
    float s=0.f;
    #pragma unroll
    for (int vv=0;vv<8;++vv) s += ls_wgt[t*8+vv];
    float inv = 1.f/fmaxf(s,1e-12f);
    #pragma unroll
    for (int vv=0;vv<8;++vv) ls_wgt[t*8+vv]*=inv;
  }
  __syncthreads();

  // ---------------- phase 1: PBR MLP, 4 chunks of 8 rows (96 samples) ----------------
  for (int ch=0; ch<4; ++ch){
    // geometry + pin K-pad re-zero (pbrF store clobbered pads last chunk)
    for (int i=t;i<96*24;i+=NTHR){ int rr=i/24, c=8+i%24; pin[rr*SPIN+c]=0; }
    if (t < 96){
      int rl = t/12, s = t%12;
      int r = ch*8 + rl;
      int Pp = p0 + (r>>3), n = r&7;
      const float* il = P.IL + ((size_t)Pp*12 + s)*7;
      float ax=il[0], ay=il[1], az=il[2];
      float sharp = __fdividef(1.f, tanhw(il[3]) + 0.1f);
      float i0=tanhw(il[4]);
      float i1=tanhw(il[5]);
      float i2=tanhw(il[6]);
      const float* nr = P.normal + ((size_t)Pp*12 + s)*3;
      float nx=nr[0], ny=nr[1], nz=nr[2];
      const float* vdp = P.view_dir + ((size_t)Pp*8 + n)*3;
      float vx=vdp[0], vy=vdp[1], vz=vdp[2];
      float hx=ax+vx, hy=ay+vy, hz=az+vz;
      float hn = sqrtf(hx*hx+hy*hy+hz*hz);
      float inv = __fdividef(1.f, fmaxf(hn, 1e-12f));
      hx*=inv; hy*=inv; hz*=inv;
      float NdotL = ax*nx+ay*ny+az*nz;
      float NdotV = vx*nx+vy*ny+vz*nz;
      float NdotH = nx*hx+ny*hy+nz*hz;
      float hdotV = hx*vx+hy*vy+hz*vz;
      float fres = 0.95f*exp2f((-5.55472f*hdotV - 6.98316f)*hdotV) + 0.05f;
      unsigned short* pp = &pin[t*SPIN];
      pp[0]=f2b(NdotL); pp[1]=f2b(sharp); pp[2]=f2b(i0); pp[3]=f2b(i1); pp[4]=f2b(i2);
      pp[5]=f2b(NdotH*NdotH); pp[6]=f2b(NdotV); pp[7]=f2b(fres);
      ls_mask[t] = (NdotL*(i0+i1+i2) > 0.f) ? 1.f : 0.f;
    }
    __syncthreads();                                   // B1
    // L1: 6mt x 4nt, K=32 (padded from 8)  -> hbuf
    #pragma unroll
    for (int q=0;q<3;++q){
      int u = w + q*8;
      int mt = u>>2, nt = u&3;
      bf16x8 a = afrag(pin, SPIN, mt*16, 0, lane);
      f32x4 d = {0.f,0.f,0.f,0.f};
      d = MFMA(a, bfrag(wsPW1, 4, 0, nt, lane), d);
      int col = nt*16 + (lane&15);
      #pragma unroll
      for (int jj=0;jj<4;++jj){
        int sm = mt*16 + ((lane>>4)<<2) + jj;
        hbuf[sm*SH+col] = f2b(eluf(d[jj] + ls_pb1[col]));
      }
    }
    __syncthreads();                                   // B2
    // L2: 6mt x 4nt, K=64 -> regs -> hbuf in place
    {
      f32x4 dq[3];
      #pragma unroll
      for (int q=0;q<3;++q){
        int u = w + q*8;
        int mt = u>>2, nt = u&3;
        f32x4 d = {0.f,0.f,0.f,0.f};
        #pragma unroll
        for (int kt=0;kt<2;++kt)
          d = MFMA(afrag(hbuf, SH, mt*16, kt, lane), bfrag(wsPW2, 4, kt, nt, lane), d);
        dq[q] = d;
      }
      __syncthreads();                                 // B3
      #pragma unroll
      for (int q=0;q<3;++q){
        int u = w + q*8;
        int mt = u>>2, nt = u&3;
        int col = nt*16 + (lane&15);
        #pragma unroll
        for (int jj=0;jj<4;++jj){
          int sm = mt*16 + ((lane>>4)<<2) + jj;
          hbuf[sm*SH+col] = f2b(eluf(dq[q][jj] + ls_pb2[col]));
        }
      }
    }
    __syncthreads();                                   // B4
    // L3: 6mt x 2nt, K=64 -> regs
    {
      f32x4 d0={0.f,0.f,0.f,0.f}, d1={0.f,0.f,0.f,0.f};
      {
        int u = w;          // q=0, always <12
        int mt = u>>1, nt = u&1;
        #pragma unroll
        for (int kt=0;kt<2;++kt)
          d0 = MFMA(afrag(hbuf, SH, mt*16, kt, lane), bfrag(wsPW3, 2, kt, nt, lane), d0);
      }
      if (w < 4){
        int u = w + 8;
        int mt = u>>1, nt = u&1;
        #pragma unroll
        for (int kt=0;kt<2;++kt)
          d1 = MFMA(afrag(hbuf, SH, mt*16, kt, lane), bfrag(wsPW3, 2, kt, nt, lane), d1);
      }
      __syncthreads();                                 // B5 (hbuf reads done; pbrF clobbers)
      {
        int u = w;
        int mt = u>>1, nt = u&1;
        int col = nt*16 + (lane&15);
        #pragma unroll
        for (int jj=0;jj<4;++jj){
          int sm = mt*16 + ((lane>>4)<<2) + jj;
          pbrF[sm*33+col] = (d0[jj] + ls_pb3[col]) * ls_mask[sm];
        }
      }
      if (w < 4){
        int u = w + 8;
        int mt = u>>1, nt = u&1;
        int col = nt*16 + (lane&15);
        #pragma unroll
        for (int jj=0;jj<4;++jj){
          int sm = mt*16 + ((lane>>4)<<2) + jj;
          pbrF[sm*33+col] = (d1[jj] + ls_pb3[col]) * ls_mask[sm];
        }
      }
    }
    __syncthreads();                                   // B6
    // reduce 12 s-samples -> light rows ch*8..ch*8+7
    if (t < 256){
      int rr = t>>5, c = t&31;
      float acc = 0.f;
      #pragma unroll
      for (int s=0;s<12;++s) acc += pbrF[(rr*12+s)*33+c];
      lightF[(ch*8+rr)*33+c] = acc;
    }
    __syncthreads();                                   // B7
  }

  // ---------------- phase 2: assemble x_input ----------------
  for (int i=t;i<RB*3;i+=NTHR){
    int r=i/3, c=i%3;
    ls_xin[r*SXIN+c] = f2b(P.rgb[((size_t)(p0+(r>>3))*8 + (r&7))*3 + c]);
  }
  for (int i=t;i<RB*32;i+=NTHR){
    int r=i>>5, c=i&31;
    ls_xin[r*SXIN+3+c] = f2b(lightF[r*33+c]);
  }
  for (int i=t;i<RB*128;i+=NTHR){
    int r=i>>7, c=i&127;
    ls_xin[r*SXIN+35+c] = f2b(P.feat[(size_t)c*NPIX + p0 + (r>>3)]);
  }
  __syncthreads();

  // ---------------- main layers ----------------
  for (int L=0; L<2; ++L){
    const unsigned short* xsrc = (L==0)? ls_xin : ls_x;
    ln_stats(xsrc, SXIN, RB, ls_stats, t);
    for (int i=t;i<192;i+=NTHR){
      ls_lnS[i] = (i<163)? P.lnv_s[L*163+i] : 0.f;
      ls_lnB[i] = (i<163)? P.lnv_b[L*163+i] : 0.f;
    }
    __syncthreads();
    // Wv: 2mt x 2nt, K=192  (A affine) -> vbuf f32
    if (w < 4){
      int mt = w&1, nt = w>>1;
      f32x4 d = {0.f,0.f,0.f,0.f};
      #pragma unroll
      for (int kt=0;kt<6;++kt){
        bf16x8 a = afrag_ln(xsrc, SXIN, mt*16, kt, lane, ls_stats, ls_lnS, ls_lnB);
        d = MFMA(a, bfrag(wsWv[L], 2, kt, nt, lane), d);
      }
      int col = nt*16 + (lane&15);
      #pragma unroll
      for (int jj=0;jj<4;++jj){
        int row = mt*16 + ((lane>>4)<<2) + jj;
        vbuf[row*36+col] = d[jj];
      }
    }
    __syncthreads();

    if (L==0){
      // build x96 = [v | m | var]; zero ls_x pad cols (light is dead now); stage bout
      for (int i=t;i<RB*32;i+=NTHR){ int rr=i>>5, c=i&31; x96[rr*SX96+c] = f2b(vbuf[rr*36+c]); }
      if (t < 128){
        int px=t>>5, c=t&31;
        float m=0.f;
        #pragma unroll
        for (int vv=0;vv<8;++vv) m += ls_wgt[px*8+vv]*vbuf[(px*8+vv)*36+c];
        float va=0.f;
        #pragma unroll
        for (int vv=0;vv<8;++vv){ float dd=vbuf[(px*8+vv)*36+c]-m; va += ls_wgt[px*8+vv]*dd*dd; }
        unsigned short mb=f2b(m), vb=f2b(va);
        #pragma unroll
        for (int vv=0;vv<8;++vv){ int rr=px*8+vv; x96[rr*SX96+32+c]=mb; x96[rr*SX96+64+c]=vb; }
      }
      for (int i=t;i<RB*37;i+=NTHR){ int rr=i/37, c=163+i%37; ls_x[rr*SX+c]=0; }
      for (int i=t;i<163;i+=NTHR) ls_bias[i] = P.bout[i];
      __syncthreads();
      // Wout: 2mt x 11nt, K=96 -> ls_x (+bout +xin)
      {
        int mt = w&1;
        bf16x8 a[3];
        #pragma unroll
        for (int kt=0;kt<3;++kt) a[kt] = afrag(x96, SX96, mt*16, kt, lane);
        for (int nt=(w>>1); nt<11; nt+=4){
          f32x4 d = {0.f,0.f,0.f,0.f};
          #pragma unroll
          for (int kt=0;kt<3;++kt) d = MFMA(a[kt], bfrag(wsWo[0], 11, kt, nt, lane), d);
          int col = nt*16 + (lane&15);
          if (col < 163){
            #pragma unroll
            for (int jj=0;jj<4;++jj){
              int row = mt*16 + ((lane>>4)<<2) + jj;
              ls_x[row*SX+col] = f2b(d[jj] + ls_bias[col] + b2f(ls_xin[row*SXIN+col]));
            }
          }
        }
      }
      __syncthreads();
      ln_stats(ls_x, SX, RB, ls_stats, t);
      for (int i=t;i<192;i+=NTHR){
        ls_lnS[i] = (i<163)? P.lnn_s[i] : 0.f;
        ls_lnB[i] = (i<163)? P.lnn_b[i] : 0.f;
      }
      for (int i=t;i<256;i+=NTHR) ls_bias[i] = P.b1[i];
      for (int i=t;i<163;i+=NTHR) ls_bias2[i] = P.b2[i];
      __syncthreads();
      // W1: 2mt x 16nt, K=192 (A affine) -> ybuf = gelu
      {
        int mt = w&1;
        bf16x8 a[6];
        #pragma unroll
        for (int kt=0;kt<6;++kt) a[kt] = afrag_ln(ls_x, SX, mt*16, kt, lane, ls_stats, ls_lnS, ls_lnB);
        for (int nt=(w>>1); nt<16; nt+=4){
          f32x4 d = {0.f,0.f,0.f,0.f};
          #pragma unroll
          for (int kt=0;kt<6;++kt) d = MFMA(a[kt], bfrag(wsW1[0], 16, kt, nt, lane), d);
          int col = nt*16 + (lane&15);
          #pragma unroll
          for (int jj=0;jj<4;++jj){
            int row = mt*16 + ((lane>>4)<<2) + jj;
            ybuf[row*SY+col] = f2b(geluf(d[jj] + ls_bias[col]));
          }
        }
      }
      __syncthreads();
      // W2: 2mt x 11nt, K=256 -> ls_x (+b2 +xin). kh-split caps VGPR pressure.
      {
        int mt = w&1, ntb = w>>1;
        f32x4 dd0={0.f,0.f,0.f,0.f}, dd1={0.f,0.f,0.f,0.f}, dd2={0.f,0.f,0.f,0.f};
        #pragma unroll
        for (int kh=0; kh<2; ++kh){
          bf16x8 a[4];
          #pragma unroll
          for (int k2=0;k2<4;++k2) a[k2] = afrag(ybuf, SY, mt*16, kh*4+k2, lane);
          #pragma unroll
          for (int k2=0;k2<4;++k2) dd0 = MFMA(a[k2], bfrag(wsW2[0], 11, kh*4+k2, ntb, lane), dd0);
          #pragma unroll
          for (int k2=0;k2<4;++k2) dd1 = MFMA(a[k2], bfrag(wsW2[0], 11, kh*4+k2, ntb+4, lane), dd1);
          if (ntb < 3){
            #pragma unroll
            for (int k2=0;k2<4;++k2) dd2 = MFMA(a[k2], bfrag(wsW2[0], 11, kh*4+k2, ntb+8, lane), dd2);
          }
        }
        #pragma unroll
        for (int j=0;j<3;++j){
          int nt = ntb + 4*j;
          if (nt < 11){
            f32x4 d = (j==0)? dd0 : (j==1)? dd1 : dd2;
            int col = nt*16 + (lane&15);
            if (col < 163){
              #pragma unroll
              for (int jj=0;jj<4;++jj){
                int row = mt*16 + ((lane>>4)<<2) + jj;
                ls_x[row*SX+col] = f2b(d[jj] + ls_bias2[col] + b2f(ls_xin[row*SXIN+col]));
              }
            }
          }
        }
      }
      __syncthreads();
    } else {
      // layer 1 tail: row0 only per pixel
      if (t < 128){
        int px=t>>5, c=t&31;
        float m=0.f;
        #pragma unroll
        for (int vv=0;vv<8;++vv) m += ls_wgt[px*8+vv]*vbuf[(px*8+vv)*36+c];
        float va=0.f;
        #pragma unroll
        for (int vv=0;vv<8;++vv){ float dd=vbuf[(px*8+vv)*36+c]-m; va += ls_wgt[px*8+vv]*dd*dd; }
        x96r0[px*SX96+c]    = f2b(vbuf[(px*8)*36+c]);
        x96r0[px*SX96+32+c] = f2b(m);
        x96r0[px*SX96+64+c] = f2b(va);
      }
      for (int i=t;i<16*37;i+=NTHR){ int rr=i/37, c=163+i%37; x8[rr*SX8+c]=0; }
      for (int i=t;i<163;i+=NTHR) ls_bias[i] = P.bout[163+i];
      __syncthreads();
      // Wout1: 1mt x 11nt, K=96 -> x8 (+bout1 +xin row0)
      {
        bf16x8 a[3];
        #pragma unroll
        for (int kt=0;kt<3;++kt) a[kt] = afrag(x96r0, SX96, 0, kt, lane);
        for (int nt=w; nt<11; nt+=8){
          f32x4 d = {0.f,0.f,0.f,0.f};
          #pragma unroll
          for (int kt=0;kt<3;++kt) d = MFMA(a[kt], bfrag(wsWo[1], 11, kt, nt, lane), d);
          int col = nt*16 + (lane&15);
          if (col < 163){
            #pragma unroll
            for (int jj=0;jj<4;++jj){
              int px = ((lane>>4)<<2) + jj;
              if (px < PXB)
                x8[px*SX8+col] = f2b(d[jj] + ls_bias[col] + b2f(ls_xin[(px*8)*SXIN+col]));
            }
          }
        }
      }
      __syncthreads();
      ln_stats(x8, SX8, 16, ls_stats, t);
      for (int i=t;i<192;i+=NTHR){
        ls_lnS[i] = (i<163)? P.lnn_s[163+i] : 0.f;
        ls_lnB[i] = (i<163)? P.lnn_b[163+i] : 0.f;
      }
      for (int i=t;i<256;i+=NTHR) ls_bias[i] = P.b1[256+i];
      for (int i=t;i<163;i+=NTHR) ls_bias2[i] = P.b2[163+i];
      __syncthreads();
      // W1_1: 1mt x 16nt K=192 affine -> y8 gelu
      {
        bf16x8 a[6];
        #pragma unroll
        for (int kt=0;kt<6;++kt) a[kt] = afrag_ln(x8, SX8, 0, kt, lane, ls_stats, ls_lnS, ls_lnB);
        for (int nt=w; nt<16; nt+=8){
          f32x4 d = {0.f,0.f,0.f,0.f};
          #pragma unroll
          for (int kt=0;kt<6;++kt) d = MFMA(a[kt], bfrag(wsW1[1], 16, kt, nt, lane), d);
          int col = nt*16 + (lane&15);
          #pragma unroll
          for (int jj=0;jj<4;++jj){
            int row = ((lane>>4)<<2) + jj;
            y8[row*SY+col] = f2b(geluf(d[jj] + ls_bias[col]));
          }
        }
      }
      __syncthreads();
      // W2_1: 1mt x 11nt K=256 -> x8 (+b2_1 +xin row0), kh-split
      {
        f32x4 dd0={0.f,0.f,0.f,0.f}, dd1={0.f,0.f,0.f,0.f};
        #pragma unroll
        for (int kh=0; kh<2; ++kh){
          bf16x8 a[4];
          #pragma unroll
          for (int k2=0;k2<4;++k2) a[k2] = afrag(y8, SY, 0, kh*4+k2, lane);
          #pragma unroll
          for (int k2=0;k2<4;++k2) dd0 = MFMA(a[k2], bfrag(wsW2[1], 11, kh*4+k2, w, lane), dd0);
          if (w < 3){
            #pragma unroll
            for (int k2=0;k2<4;++k2) dd1 = MFMA(a[k2], bfrag(wsW2[1], 11, kh*4+k2, w+8, lane), dd1);
          }
        }
        #pragma unroll
        for (int j=0;j<2;++j){
          int nt = w + 8*j;
          if (nt < 11){
            f32x4 d = (j==0)? dd0 : dd1;
            int col = nt*16 + (lane&15);
            if (col < 163){
              #pragma unroll
              for (int jj=0;jj<4;++jj){
                int px = ((lane>>4)<<2) + jj;
                if (px < PXB)
                  x8[px*SX8+col] = f2b(d[jj] + ls_bias2[col] + b2f(ls_xin[(px*8)*SXIN+col]));
              }
            }
          }
        }
      }
      __syncthreads();
    }
  }

  // ---------------- head ----------------
  ln_stats(x8, SX8, 16, ls_stats, t);
  for (int i=t;i<192;i+=NTHR){
    ls_lnS[i] = (i<163)? P.lnb_s[i] : 0.f;
    ls_lnB[i] = (i<163)? P.lnb_b[i] : 0.f;
  }
  for (int i=t;i<128;i+=NTHR){ ls_bias[i] = P.bb1[i]; ls_bias2[i] = P.bb2[i]; }
  __syncthreads();
  // Wb1: K=192 affine, 8nt -> y8 gelu
  {
    int nt = w;
    f32x4 d = {0.f,0.f,0.f,0.f};
    #pragma unroll
    for (int kt=0;kt<6;++kt){
      bf16x8 a = afrag_ln(x8, SX8, 0, kt, lane, ls_stats, ls_lnS, ls_lnB);
      d = MFMA(a, bfrag(ws+OFF_WB1, 8, kt, nt, lane), d);
    }
    int col = nt*16 + (lane&15);
    #pragma unroll
    for (int jj=0;jj<4;++jj){
      int row = ((lane>>4)<<2) + jj;
      y8[row*SY+col] = f2b(geluf(d[jj] + ls_bias[col]));
    }
  }
  __syncthreads();
  // Wb2: K=128, 8nt -> regs -> y8 gelu ; stage bb3
  {
    int nt = w;
    f32x4 d = {0.f,0.f,0.f,0.f};
    #pragma unroll
    for (int kt=0;kt<4;++kt)
      d = MFMA(afrag(y8, SY, 0, kt, lane), bfrag(ws+OFF_WB2, 8, kt, nt, lane), d);
    __syncthreads();
    int col = nt*16 + (lane&15);
    #pragma unroll
    for (int jj=0;jj<4;++jj){
      int row = ((lane>>4)<<2) + jj;
      y8[row*SY+col] = f2b(geluf(d[jj] + ls_bias2[col]));
    }
    for (int i=t;i<64;i+=NTHR) ls_bias[i] = P.bb3[i];
  }
  __syncthreads();
  // Wb3: K=128, 4nt -> global out
  if (w < 4){
    int nt = w;
    f32x4 d = {0.f,0.f,0.f,0.f};
    #pragma unroll
    for (int kt=0;kt<4;++kt)
      d = MFMA(afrag(y8, SY, 0, kt, lane), bfrag(ws+OFF_WB3, 4, kt, nt, lane), d);
    int col = nt*16 + (lane&15);
    #pragma unroll
    for (int jj=0;jj<4;++jj){
      int px = ((lane>>4)<<2) + jj;
      if (px < PXB)
        P.out[(size_t)col*NPIX + p0 + px] = d[jj] + ls_bias[col];
    }
  }
}

// ================= fallback (fp32 kernel) for tiny ws =================
__device__ __forceinline__ float gelu_fb(float x){ return 0.5f*x*(1.0f+erff(x*0.70710678118654752f)); }
__device__ __forceinline__ float elu_fb(float x){ return x>0.0f ? x : expm1f(x); }

__device__ __forceinline__ void ln_rows_fb(const float* xT, float* xnT, int nrows,
                                           const float* sc, const float* bi,
                                           float* s_ln, int t)
{
  int r = t>>5, ln = t&31;
  if (r < nrows){
    float sm=0.f, sq=0.f;
    for (int k=ln;k<DIM;k+=32){ float v=xT[k*8+r]; sm+=v; sq+=v*v; }
    #pragma unroll
    for (int off=16;off;off>>=1){ sm+=__shfl_xor(sm,off,32); sq+=__shfl_xor(sq,off,32); }
    if (ln==0){
      float mean = sm*(1.f/163.f);
      float var  = sq*(1.f/163.f) - mean*mean;
      s_ln[r*2]=mean; s_ln[r*2+1]=rsqrtf(var+1e-5f);
    }
  }
  __syncthreads();
  for (int i=t;i<nrows*DIM;i+=256){
    int rr=i/DIM, c=i-rr*DIM;
    float v=(xT[c*8+rr]-s_ln[rr*2])*s_ln[rr*2+1];
    xnT[c*8+rr]=v*sc[c]+bi[c];
  }
  __syncthreads();
}

__global__ __launch_bounds__(256)
void aggnet_fallback(Params P)
{
  const int t = threadIdx.x;
  const int p = blockIdx.x;
  __shared__ float s_pbrw[6816];
  __shared__ float s_pin[96*8];
  __shared__ float s_mask[96];
  __shared__ float s_h[256];
  __shared__ float s_h2[256];
  __shared__ float s_pbr[96*32];
  __shared__ float s_xinT[DIM*8];
  __shared__ float s_xT[DIM*8];
  __shared__ float s_xnT[DIM*8];
  __shared__ float s_x96T[96*8];
  __shared__ float s_yT[256*8];
  __shared__ float s_wgt[8];
  __shared__ float s_ln[16];

  for (int i=t;i<512;i+=256)  s_pbrw[i]      = P.pw1[i];
  for (int i=t;i<64;i+=256)   s_pbrw[512+i]  = P.pb1[i];
  for (int i=t;i<4096;i+=256) s_pbrw[576+i]  = P.pw2[i];
  for (int i=t;i<64;i+=256)   s_pbrw[4672+i] = P.pb2[i];
  for (int i=t;i<2048;i+=256) s_pbrw[4736+i] = P.pw3[i];
  for (int i=t;i<32;i+=256)   s_pbrw[6784+i] = P.pb3[i];
  if (t < 96){
    int n = t/12, s = t - n*12;
    const float* il = P.IL + (p*12 + s)*7;
    float ax=il[0], ay=il[1], az=il[2];
    float sharp = 1.f/(tanf(1.5692255304681f*il[3]) + 0.1f);
    float i0=tanf(1.5692255304681f*il[4]);
    float i1=tanf(1.5692255304681f*il[5]);
    float i2=tanf(1.5692255304681f*il[6]);
    const float* nr = P.normal + (p*12 + s)*3;
    float nx=nr[0], ny=nr[1], nz=nr[2];
    const float* vdp = P.view_dir + (p*8 + n)*3;
    float vx=vdp[0], vy=vdp[1], vz=vdp[2];
    float hx=ax+vx, hy=ay+vy, hz=az+vz;
    float hn = sqrtf(hx*hx+hy*hy+hz*hz);
    float inv = 1.f/fmaxf(hn, 1e-12f);
    hx*=inv; hy*=inv; hz*=inv;
    float NdotL = ax*nx+ay*ny+az*nz;
    float NdotV = vx*nx+vy*ny+vz*nz;
    float NdotH = nx*hx+ny*hy+nz*hz;
    float hdotV = hx*vx+hy*vy+hz*vz;
    float fres = 0.95f*exp2f((-5.55472f*hdotV - 6.98316f)*hdotV) + 0.05f;
    float* pi2 = &s_pin[t*8];
    pi2[0]=NdotL; pi2[1]=sharp; pi2[2]=i0; pi2[3]=i1; pi2[4]=i2;
    pi2[5]=NdotH*NdotH; pi2[6]=NdotV; pi2[7]=fres;
    s_mask[t] = (NdotL*(i0+i1+i2) > 0.f) ? 1.f : 0.f;
  }
  if (t>=96 && t<104){
    int r=t-96;
    float pe = P.proj_err[p*8+r];
    s_wgt[r] = -fminf(log10f(fabsf(pe)+1e-6f), 0.f);
  }
  __syncthreads();
  if (t==0){
    float s=0.f;
    #pragma unroll
    for (int r=0;r<8;++r) s += s_wgt[r];
    float inv = 1.f/fmaxf(s,1e-12f);
    #pragma unroll
    for (int r=0;r<8;++r) s_wgt[r]*=inv;
  }
  __syncthreads();
  {
    const int sl = t>>6, j = t&63;
    for (int ch=0; ch<24; ++ch){
      const int g = ch*4 + sl;
      float acc = s_pbrw[512+j];
      #pragma unroll
      for (int k=0;k<8;++k) acc += s_pin[g*8+k]*s_pbrw[k*64+j];
      s_h[sl*64+j] = elu_fb(acc);
      __syncthreads();
      acc = s_pbrw[4672+j];
      #pragma unroll
      for (int k=0;k<64;++k) acc += s_h[sl*64+k]*s_pbrw[576+k*64+j];
      s_h2[sl*64+j] = elu_fb(acc);
      __syncthreads();
      if (t<128){
        int sm=t>>5, cc=t&31;
        int g2 = ch*4+sm;
        float a = s_pbrw[6784+cc];
        #pragma unroll
        for (int k=0;k<64;++k) a += s_h2[sm*64+k]*s_pbrw[4736+k*32+cc];
        s_pbr[g2*32+cc] = s_mask[g2]*a;
      }
      __syncthreads();
    }
  }
  {
    int n=t>>5, c=t&31;
    float lt=0.f;
    #pragma unroll
    for (int s=0;s<12;++s) lt += s_pbr[(n*12+s)*32+c];
    s_xinT[(3+c)*8+n] = lt;
    if (t<24){ int r=t/3, cc=t-r*3; s_xinT[cc*8+r] = P.rgb[(p*8+r)*3+cc]; }
    for (int i=t;i<1024;i+=256){ int cc=i>>3, r=i&7; s_xinT[(35+cc)*8+r] = P.feat[cc*NPIX+p]; }
  }
  __syncthreads();
  for (int i=t;i<DIM*8;i+=256) s_xT[i]=s_xinT[i];
  __syncthreads();
  for (int L=0; L<2; ++L){
    ln_rows_fb(s_xT, s_xnT, 8, P.lnv_s+L*DIM, P.lnv_b+L*DIM, s_ln, t);
    {
      int r=t>>5, c=t&31;
      const float* wv = P.Wv + L*DIM*32;
      float acc=0.f;
      for (int k=0;k<DIM;++k) acc += s_xnT[k*8+r]*wv[k*32+c];
      s_x96T[c*8+r]=acc;
    }
    __syncthreads();
    if (t<32){
      float m=0.f;
      #pragma unroll
      for (int r=0;r<8;++r) m += s_x96T[t*8+r]*s_wgt[r];
      float va=0.f;
      #pragma unroll
      for (int r=0;r<8;++r){ float d=s_x96T[t*8+r]-m; va+=s_wgt[r]*d*d; }
      #pragma unroll
      for (int r=0;r<8;++r){ s_x96T[(32+t)*8+r]=m; s_x96T[(64+t)*8+r]=va; }
    }
    __syncthreads();
    if (L==0){
      for (int i=t;i<DIM*8;i+=256){
        int r=i/DIM, c=i-r*DIM;
        float acc = P.bout[c] + s_xinT[c*8+r];
        for (int k=0;k<96;++k) acc += s_x96T[k*8+r]*P.Wout[k*DIM+c];
        s_xT[c*8+r]=acc;
      }
      __syncthreads();
      ln_rows_fb(s_xT, s_xnT, 8, P.lnn_s, P.lnn_b, s_ln, t);
      {
        int c=t;
        float b1v = P.b1[c];
        float acc[8];
        #pragma unroll
        for (int r=0;r<8;++r) acc[r]=b1v;
        for (int k=0;k<DIM;++k){
          float wv = P.W1[k*256+c];
          const float4* xp = (const float4*)&s_xnT[k*8];
          float4 a=xp[0], b=xp[1];
          acc[0]+=a.x*wv; acc[1]+=a.y*wv; acc[2]+=a.z*wv; acc[3]+=a.w*wv;
          acc[4]+=b.x*wv; acc[5]+=b.y*wv; acc[6]+=b.z*wv; acc[7]+=b.w*wv;
        }
        float* yp=&s_yT[c*8];
        #pragma unroll
        for (int r=0;r<8;++r) yp[r]=gelu_fb(acc[r]);
      }
      __syncthreads();
      for (int i=t;i<DIM*8;i+=256){
        int r=i/DIM, c=i-r*DIM;
        float acc = P.b2[c] + s_xinT[c*8+r];
        for (int k=0;k<256;++k) acc += s_yT[k*8+r]*P.W2[k*DIM+c];
        s_xT[c*8+r]=acc;
      }
      __syncthreads();
    } else {
      if (t<DIM){
        int c=t;
        float acc=P.bout[DIM+c] + s_xinT[c*8];
        for (int k=0;k<96;++k) acc += s_x96T[k*8]*P.Wout[96*DIM + k*DIM+c];
        s_xT[c*8]=acc;
      }
      __syncthreads();
      ln_rows_fb(s_xT, s_xnT, 1, P.lnn_s+DIM, P.lnn_b+DIM, s_ln, t);
      {
        int c=t;
        float acc=P.b1[256+c];
        for (int k=0;k<DIM;++k) acc += s_xnT[k*8]*P.W1[DIM*256 + k*256+c];
        s_yT[c*8]=gelu_fb(acc);
      }
      __syncthreads();
      if (t<DIM){
        int c=t;
        float acc=P.b2[DIM+c] + s_xinT[c*8];
        for (int k=0;k<256;++k) acc += s_yT[k*8]*P.W2[256*DIM + k*DIM+c];
        s_xT[c*8]=acc;
      }
      __syncthreads();
    }
  }
  ln_rows_fb(s_xT, s_xnT, 1, P.lnb_s, P.lnb_b, s_ln, t);
  if (t<128){
    float acc=P.bb1[t];
    for (int k=0;k<DIM;++k) acc += s_xnT[k*8]*P.Wb1[k*128+t];
    s_yT[1536+t]=gelu_fb(acc);
  }
  __syncthreads();
  if (t<128){
    float acc=P.bb2[t];
    for (int k=0;k<128;++k) acc += s_yT[1536+k]*P.Wb2[k*128+t];
    s_yT[1792+t]=gelu_fb(acc);
  }
  __syncthreads();
  if (t<64){
    float acc=P.bb3[t];
    for (int k=0;k<128;++k) acc += s_yT[1792+k]*P.Wb3[k*64+t];
    P.out[t*NPIX+p] = acc;
  }
}

extern "C" void kernel_launch(void* const* d_in, const int* in_sizes, int n_in,
                              void* d_out, int out_size, void* d_ws, size_t ws_size,
                              hipStream_t stream)
{
  Params P;
  P.rgb      = (const float*)d_in[0];
  P.proj_err = (const float*)d_in[4];
  P.feat     = (const float*)d_in[5];
  P.view_dir = (const float*)d_in[6];
  P.normal   = (const float*)d_in[7];
  P.IL       = (const float*)d_in[8];
  P.pw1=(const float*)d_in[9];  P.pb1=(const float*)d_in[10];
  P.pw2=(const float*)d_in[11]; P.pb2=(const float*)d_in[12];
  P.pw3=(const float*)d_in[13]; P.pb3=(const float*)d_in[14];
  P.lnv_s=(const float*)d_in[15]; P.lnv_b=(const float*)d_in[16];
  P.Wv=(const float*)d_in[17]; P.Wout=(const float*)d_in[18]; P.bout=(const float*)d_in[19];
  P.lnn_s=(const float*)d_in[20]; P.lnn_b=(const float*)d_in[21];
  P.W1=(const float*)d_in[22]; P.b1=(const float*)d_in[23];
  P.W2=(const float*)d_in[24]; P.b2=(const float*)d_in[25];
  P.lnb_s=(const float*)d_in[26]; P.lnb_b=(const float*)d_in[27];
  P.Wb1=(const float*)d_in[28]; P.bb1=(const float*)d_in[29];
  P.Wb2=(const float*)d_in[30]; P.bb2=(const float*)d_in[31];
  P.Wb3=(const float*)d_in[32]; P.bb3=(const float*)d_in[33];
  P.out = (float*)d_out;

  if (ws_size >= (size_t)WS_BYTES){
    unsigned short* ws = (unsigned short*)d_ws;
    hipLaunchKernelGGL(conv_weights, dim3((WS_ELEMS+511)/512), dim3(512), 0, stream, P, ws);
    hipLaunchKernelGGL(aggnet_mfma, dim3(NPIX/PXB), dim3(512), 0, stream, P, (const unsigned short*)ws);
  } else {
    hipLaunchKernelGGL(aggnet_fallback, dim3(NPIX), dim3(256), 0, stream, P);
  }
}